// Round 1
// baseline (461.084 us; speedup 1.0000x reference)
//
#include <hip/hip_runtime.h>
#include <hip/hip_bf16.h>

#define N_NODES_C 50000
#define SCAN_BLOCK 512

// ---------------- CSR build ----------------

__global__ void count_deg_k(const int* __restrict__ e_row, int E, int* __restrict__ deg) {
    int i = blockIdx.x * 256 + threadIdx.x;
    if (i < E) atomicAdd(&deg[e_row[i]], 1);
}

__global__ void block_sum_k(const int* __restrict__ deg, int n, int* __restrict__ blk_sums) {
    __shared__ int s[SCAN_BLOCK];
    int i = blockIdx.x * SCAN_BLOCK + threadIdx.x;
    s[threadIdx.x] = (i < n) ? deg[i] : 0;
    __syncthreads();
    for (int off = SCAN_BLOCK / 2; off > 0; off >>= 1) {
        if (threadIdx.x < off) s[threadIdx.x] += s[threadIdx.x + off];
        __syncthreads();
    }
    if (threadIdx.x == 0) blk_sums[blockIdx.x] = s[0];
}

__global__ void scan_blk_sums_k(int* __restrict__ blk_sums, int nb, int* __restrict__ row_ptr,
                                int n, int E) {
    if (threadIdx.x == 0 && blockIdx.x == 0) {
        int acc = 0;
        for (int b = 0; b < nb; ++b) { int v = blk_sums[b]; blk_sums[b] = acc; acc += v; }
        row_ptr[n] = E;
    }
}

__global__ void scan_phase3_k(const int* __restrict__ deg, int n,
                              const int* __restrict__ blk_sums, int* __restrict__ row_ptr) {
    __shared__ int s[SCAN_BLOCK];
    int i = blockIdx.x * SCAN_BLOCK + threadIdx.x;
    int v = (i < n) ? deg[i] : 0;
    s[threadIdx.x] = v;
    __syncthreads();
    for (int off = 1; off < SCAN_BLOCK; off <<= 1) {
        int t = (threadIdx.x >= (unsigned)off) ? s[threadIdx.x - off] : 0;
        __syncthreads();
        s[threadIdx.x] += t;
        __syncthreads();
    }
    if (i < n) row_ptr[i] = blk_sums[blockIdx.x] + s[threadIdx.x] - v;  // exclusive
}

__global__ void fill_csr_k(const int* __restrict__ e_row, const int* __restrict__ e_col, int E,
                           const int* __restrict__ row_ptr, int* __restrict__ fill_cnt,
                           int* __restrict__ csr_col) {
    int i = blockIdx.x * 256 + threadIdx.x;
    if (i < E) {
        int r = e_row[i];
        int p = row_ptr[r] + atomicAdd(&fill_cnt[r], 1);
        csr_col[p] = e_col[i];
    }
}

__global__ void deg_inv_k(const int* __restrict__ deg, float* __restrict__ deg_inv, int n) {
    int i = blockIdx.x * 256 + threadIdx.x;
    if (i < n) deg_inv[i] = 1.0f / (float)(deg[i] + 1);  // +1 self loop
}

// ---------------- fuse W3@W4, b3@W4+b4 ----------------

__global__ void fuse_w34_k(const float* __restrict__ W3, const float* __restrict__ b3,
                           const float* __restrict__ W4, const float* __restrict__ b4,
                           float* __restrict__ Wf, float* __restrict__ bf) {
    int idx = blockIdx.x * 256 + threadIdx.x;
    if (idx < 128 * 64) {
        int k = idx >> 6, o = idx & 63;
        float acc = 0.f;
        for (int m = 0; m < 128; ++m) acc = fmaf(W3[k * 128 + m], W4[m * 64 + o], acc);
        Wf[idx] = acc;
    } else if (idx < 128 * 64 + 64) {
        int o = idx - 128 * 64;
        float acc = b4[o];
        for (int m = 0; m < 128; ++m) acc = fmaf(b3[m], W4[m * 64 + o], acc);
        bf[o] = acc;
    }
}

// ---------------- dense GEMM: C[n,NC] = A[n,128] @ W[128,NC] (+bias) ----------------

__device__ inline void fma4(float4& acc, float a, const float4& w) {
    acc.x = fmaf(a, w.x, acc.x);
    acc.y = fmaf(a, w.y, acc.y);
    acc.z = fmaf(a, w.z, acc.z);
    acc.w = fmaf(a, w.w, acc.w);
}

template <int NC>
__global__ __launch_bounds__(256) void gemm_k(const float* __restrict__ A,
                                              const float* __restrict__ W,
                                              const float* __restrict__ bias,
                                              float* __restrict__ C, int n) {
    constexpr int TC = NC / 4;    // threads across columns (float4 each)
    constexpr int TR = 256 / TC;  // thread rows
    constexpr int BM = TR * 4;    // rows per block
    __shared__ float4 Ws[128 * TC];
    const float4* W4 = (const float4*)W;
    for (int i = threadIdx.x; i < 128 * TC; i += 256) Ws[i] = W4[i];
    __syncthreads();

    int tc = threadIdx.x % TC;
    int tr = threadIdx.x / TC;
    int row0 = blockIdx.x * BM + tr * 4;

    int rc[4];
    float4 acc[4];
#pragma unroll
    for (int rr = 0; rr < 4; ++rr) {
        int r = row0 + rr;
        rc[rr] = r < n ? r : (n - 1);
        acc[rr] = make_float4(0.f, 0.f, 0.f, 0.f);
    }
    const float4* A4 = (const float4*)A;  // [n][32]

#pragma unroll 8
    for (int kk = 0; kk < 32; ++kk) {
        float4 w0 = Ws[(4 * kk + 0) * TC + tc];
        float4 w1 = Ws[(4 * kk + 1) * TC + tc];
        float4 w2 = Ws[(4 * kk + 2) * TC + tc];
        float4 w3 = Ws[(4 * kk + 3) * TC + tc];
#pragma unroll
        for (int rr = 0; rr < 4; ++rr) {
            float4 a = A4[(size_t)rc[rr] * 32 + kk];
            fma4(acc[rr], a.x, w0);
            fma4(acc[rr], a.y, w1);
            fma4(acc[rr], a.z, w2);
            fma4(acc[rr], a.w, w3);
        }
    }

    if (bias != nullptr) {
        float4 b = ((const float4*)bias)[tc];
#pragma unroll
        for (int rr = 0; rr < 4; ++rr) {
            acc[rr].x += b.x; acc[rr].y += b.y; acc[rr].z += b.z; acc[rr].w += b.w;
        }
    }

    float4* C4 = (float4*)C;
#pragma unroll
    for (int rr = 0; rr < 4; ++rr) {
        int r = row0 + rr;
        if (r < n) C4[(size_t)r * TC + tc] = acc[rr];
    }
}

// ---------------- SpMM mean-aggregate + bias + optional relu ----------------
// out[i,:] = relu( deg_inv[i] * (t[i,:] + sum_nb t[col,:]) + bias )

__global__ __launch_bounds__(256) void spmm_k(const float* __restrict__ t,
                                              const int* __restrict__ row_ptr,
                                              const int* __restrict__ csr_col,
                                              const float* __restrict__ deg_inv,
                                              const float* __restrict__ bias,
                                              float* __restrict__ out, int n, int do_relu) {
    int wave = threadIdx.x >> 6;
    int lane = threadIdx.x & 63;
    int row = blockIdx.x * 4 + wave;
    if (row >= n) return;

    const float2* t2 = (const float2*)t;
    float2 acc = t2[(size_t)row * 64 + lane];  // self loop
    int s = row_ptr[row], e = row_ptr[row + 1];
    int p = s;
    // 2-wide manual unroll for a bit of load ILP
    for (; p + 1 < e; p += 2) {
        int c0 = csr_col[p];
        int c1 = csr_col[p + 1];
        float2 v0 = t2[(size_t)c0 * 64 + lane];
        float2 v1 = t2[(size_t)c1 * 64 + lane];
        acc.x += v0.x + v1.x;
        acc.y += v0.y + v1.y;
    }
    if (p < e) {
        int c = csr_col[p];
        float2 v = t2[(size_t)c * 64 + lane];
        acc.x += v.x;
        acc.y += v.y;
    }
    float di = deg_inv[row];
    float2 b = ((const float2*)bias)[lane];
    float rx = fmaf(acc.x, di, b.x);
    float ry = fmaf(acc.y, di, b.y);
    if (do_relu) { rx = fmaxf(rx, 0.f); ry = fmaxf(ry, 0.f); }
    ((float2*)out)[(size_t)row * 64 + lane] = make_float2(rx, ry);
}

// ---------------- launch ----------------

extern "C" void kernel_launch(void* const* d_in, const int* in_sizes, int n_in,
                              void* d_out, int out_size, void* d_ws, size_t ws_size,
                              hipStream_t stream) {
    const float* x  = (const float*)d_in[0];
    const int* edges = (const int*)d_in[1];
    const float* W1 = (const float*)d_in[2];
    const float* b1 = (const float*)d_in[3];
    const float* W2 = (const float*)d_in[4];
    const float* b2 = (const float*)d_in[5];
    const float* W3 = (const float*)d_in[6];
    const float* b3 = (const float*)d_in[7];
    const float* W4 = (const float*)d_in[8];
    const float* b4 = (const float*)d_in[9];

    const int N = in_sizes[0] / 128;
    const int E = in_sizes[1] / 2;
    const int* e_row = edges;
    const int* e_col = edges + E;

    // carve workspace
    char* p = (char*)d_ws;
    auto alloc = [&](size_t bytes) {
        void* r = (void*)p;
        p += (bytes + 255) & ~(size_t)255;
        return r;
    };
    float* t_buf   = (float*)alloc((size_t)N * 128 * 4);
    float* h_buf   = (float*)alloc((size_t)N * 128 * 4);
    int*   deg     = (int*)alloc((size_t)N * 4);
    float* deginv  = (float*)alloc((size_t)N * 4);
    int*   row_ptr = (int*)alloc((size_t)(N + 1) * 4);
    int*   fillc   = (int*)alloc((size_t)N * 4);
    int*   csr_col = (int*)alloc((size_t)E * 4);
    float* Wf      = (float*)alloc(128 * 64 * 4);
    float* bf      = (float*)alloc(64 * 4);
    int*   blksums = (int*)alloc(4096 * 4);

    float* out = (float*)d_out;

    hipMemsetAsync(deg, 0, (size_t)N * 4, stream);
    hipMemsetAsync(fillc, 0, (size_t)N * 4, stream);

    const int nb = (N + SCAN_BLOCK - 1) / SCAN_BLOCK;

    count_deg_k<<<(E + 255) / 256, 256, 0, stream>>>(e_row, E, deg);
    block_sum_k<<<nb, SCAN_BLOCK, 0, stream>>>(deg, N, blksums);
    scan_blk_sums_k<<<1, 64, 0, stream>>>(blksums, nb, row_ptr, N, E);
    scan_phase3_k<<<nb, SCAN_BLOCK, 0, stream>>>(deg, N, blksums, row_ptr);
    fill_csr_k<<<(E + 255) / 256, 256, 0, stream>>>(e_row, e_col, E, row_ptr, fillc, csr_col);
    deg_inv_k<<<(N + 255) / 256, 256, 0, stream>>>(deg, deginv, N);

    fuse_w34_k<<<(128 * 64 + 64 + 255) / 256, 256, 0, stream>>>(W3, b3, W4, b4, Wf, bf);

    // layer 1: t1 = x @ W1 ; h1 = relu(D^-1 A t1 + b1)
    gemm_k<128><<<(N + 31) / 32, 256, 0, stream>>>(x, W1, nullptr, t_buf, N);
    spmm_k<<<(N + 3) / 4, 256, 0, stream>>>(t_buf, row_ptr, csr_col, deginv, b1, h_buf, N, 1);

    // layer 2
    gemm_k<128><<<(N + 31) / 32, 256, 0, stream>>>(h_buf, W2, nullptr, t_buf, N);
    spmm_k<<<(N + 3) / 4, 256, 0, stream>>>(t_buf, row_ptr, csr_col, deginv, b2, h_buf, N, 1);

    // post_mp fused: out = h2 @ (W3@W4) + (b3@W4+b4)
    gemm_k<64><<<(N + 63) / 64, 256, 0, stream>>>(h_buf, Wf, bf, out, N);
}

// Round 2
// 423.556 us; speedup vs baseline: 1.0886x; 1.0886x over previous
//
#include <hip/hip_runtime.h>
#include <hip/hip_bf16.h>

#define SCAN_BLOCK 512

typedef __attribute__((ext_vector_type(8))) short short8_t;
typedef __attribute__((ext_vector_type(8))) unsigned short ushort8_t;
typedef __attribute__((ext_vector_type(4))) float f32x4;

__device__ inline unsigned short bf16_rne(float f) {
    union { float f; unsigned u; } x; x.f = f;
    unsigned r = x.u + 0x7fffu + ((x.u >> 16) & 1u);
    return (unsigned short)(r >> 16);
}
__device__ inline float bf16_to_f32(unsigned short h) {
    union { unsigned u; float f; } x; x.u = ((unsigned)h) << 16;
    return x.f;
}

// ---------------- CSR build ----------------

__global__ void count_deg_k(const int* __restrict__ e_row, int E, int* __restrict__ deg) {
    int i = blockIdx.x * 256 + threadIdx.x;
    if (i < E) atomicAdd(&deg[e_row[i]], 1);
}

__global__ void block_sum_k(const int* __restrict__ deg, int n, int* __restrict__ blk_sums) {
    __shared__ int s[SCAN_BLOCK];
    int i = blockIdx.x * SCAN_BLOCK + threadIdx.x;
    s[threadIdx.x] = (i < n) ? deg[i] : 0;
    __syncthreads();
    for (int off = SCAN_BLOCK / 2; off > 0; off >>= 1) {
        if (threadIdx.x < off) s[threadIdx.x] += s[threadIdx.x + off];
        __syncthreads();
    }
    if (threadIdx.x == 0) blk_sums[blockIdx.x] = s[0];
}

__global__ void scan_blk_sums_k(int* __restrict__ blk_sums, int nb, int* __restrict__ row_ptr,
                                int n, int E) {
    if (threadIdx.x == 0 && blockIdx.x == 0) {
        int acc = 0;
        for (int b = 0; b < nb; ++b) { int v = blk_sums[b]; blk_sums[b] = acc; acc += v; }
        row_ptr[n] = E;
    }
}

__global__ void scan_phase3_k(const int* __restrict__ deg, int n,
                              const int* __restrict__ blk_sums, int* __restrict__ row_ptr) {
    __shared__ int s[SCAN_BLOCK];
    int i = blockIdx.x * SCAN_BLOCK + threadIdx.x;
    int v = (i < n) ? deg[i] : 0;
    s[threadIdx.x] = v;
    __syncthreads();
    for (int off = 1; off < SCAN_BLOCK; off <<= 1) {
        int t = (threadIdx.x >= (unsigned)off) ? s[threadIdx.x - off] : 0;
        __syncthreads();
        s[threadIdx.x] += t;
        __syncthreads();
    }
    if (i < n) row_ptr[i] = blk_sums[blockIdx.x] + s[threadIdx.x] - v;  // exclusive
}

__global__ void fill_csr_k(const int* __restrict__ e_row, const int* __restrict__ e_col, int E,
                           const int* __restrict__ row_ptr, int* __restrict__ fill_cnt,
                           int* __restrict__ csr_col) {
    int i = blockIdx.x * 256 + threadIdx.x;
    if (i < E) {
        int r = e_row[i];
        int p = row_ptr[r] + atomicAdd(&fill_cnt[r], 1);
        csr_col[p] = e_col[i];
    }
}

__global__ void deg_inv_k(const int* __restrict__ deg, float* __restrict__ deg_inv, int n) {
    int i = blockIdx.x * 256 + threadIdx.x;
    if (i < n) deg_inv[i] = 1.0f / (float)(deg[i] + 1);  // +1 self loop
}

// ---------------- weight prep: split f32 -> bf16 hi/lo, transposed [NC][128] ----------------

__global__ void split_w_k(const float* __restrict__ W, int NC,
                          unsigned short* __restrict__ hi_t, unsigned short* __restrict__ lo_t) {
    int idx = blockIdx.x * 256 + threadIdx.x;
    if (idx < 128 * NC) {
        int k = idx / NC, c = idx % NC;
        float wv = W[idx];
        unsigned short h = bf16_rne(wv);
        hi_t[c * 128 + k] = h;
        lo_t[c * 128 + k] = bf16_rne(wv - bf16_to_f32(h));
    }
}

// fuse W3@W4 (+ b3@W4+b4), emit split/transposed bf16 [64][128]
__global__ void fuse_w34_k(const float* __restrict__ W3, const float* __restrict__ b3,
                           const float* __restrict__ W4, const float* __restrict__ b4,
                           unsigned short* __restrict__ Wf_hi, unsigned short* __restrict__ Wf_lo,
                           float* __restrict__ bfv) {
    int idx = blockIdx.x * 256 + threadIdx.x;
    if (idx < 128 * 64) {
        int k = idx >> 6, o = idx & 63;
        float acc = 0.f;
        for (int m = 0; m < 128; ++m) acc = fmaf(W3[k * 128 + m], W4[m * 64 + o], acc);
        unsigned short h = bf16_rne(acc);
        Wf_hi[o * 128 + k] = h;
        Wf_lo[o * 128 + k] = bf16_rne(acc - bf16_to_f32(h));
    } else if (idx < 128 * 64 + 64) {
        int o = idx - 128 * 64;
        float acc = b4[o];
        for (int m = 0; m < 128; ++m) acc = fmaf(b3[m], W4[m * 64 + o], acc);
        bfv[o] = acc;
    }
}

// ---------------- GEMM via split-bf16 MFMA: C[n,NC] = A[n,128] @ W[128,NC] (+bias) ----------------
// W supplied pre-split + pre-transposed: Whi/Wlo are [NC][128] bf16 bits.
// a*b ~= a_hi*b_hi + a_lo*b_hi + a_hi*b_lo  (f32-class accuracy, ~2^-17 rel)

template <int NC>
__global__ __launch_bounds__(256) void gemm_mfma_k(const float* __restrict__ A,
                                                   const unsigned short* __restrict__ Whi,
                                                   const unsigned short* __restrict__ Wlo,
                                                   const float* __restrict__ bias,
                                                   float* __restrict__ C, int n) {
    constexpr int CT = NC / 16;          // 16-col tiles per row-block
    __shared__ unsigned short Ah[64 * 128];   // XOR-swizzled: byte ^= (row&7)<<4
    __shared__ unsigned short Al[64 * 128];
    const int t = threadIdx.x;
    const int row0 = blockIdx.x * 64;

    // stage + convert + split the 64x128 f32 A-tile into LDS (swizzled)
#pragma unroll
    for (int it = 0; it < 4; ++it) {
        int idx = it * 2048 + t * 8;     // element index within tile
        int rl = idx >> 7;               // local row
        int cl = idx & 127;              // col (multiple of 8)
        int gr = row0 + rl; if (gr > n - 1) gr = n - 1;
        const float4* src = (const float4*)(A + (size_t)gr * 128 + cl);
        float4 v0 = src[0];
        float4 v1 = src[1];
        float f[8] = {v0.x, v0.y, v0.z, v0.w, v1.x, v1.y, v1.z, v1.w};
        ushort8_t vh, vl;
#pragma unroll
        for (int j = 0; j < 8; ++j) {
            unsigned short h = bf16_rne(f[j]);
            vh[j] = h;
            vl[j] = bf16_rne(f[j] - bf16_to_f32(h));
        }
        int byte = rl * 256 + ((cl * 2) ^ ((rl & 7) << 4));
        *(ushort8_t*)(&Ah[byte >> 1]) = vh;
        *(ushort8_t*)(&Al[byte >> 1]) = vl;
    }
    __syncthreads();

    const int w = t >> 6;                 // wave id: rows [w*16, w*16+16)
    const int l = t & 63;
    const int col = l & 15;
    const int kg = l >> 4;                // k-group (8 bf16 each)
    const int rloc = w * 16 + col;        // A-frag row for this lane

    f32x4 acc[CT];
#pragma unroll
    for (int ct = 0; ct < CT; ++ct) acc[ct] = (f32x4){0.f, 0.f, 0.f, 0.f};

#pragma unroll
    for (int ks = 0; ks < 4; ++ks) {
        int abyte = rloc * 256 + ((ks * 64 + kg * 16) ^ ((rloc & 7) << 4));
        short8_t ah = *(const short8_t*)(&Ah[abyte >> 1]);
        short8_t al = *(const short8_t*)(&Al[abyte >> 1]);
#pragma unroll
        for (int ct = 0; ct < CT; ++ct) {
            const size_t wo = (size_t)(ct * 16 + col) * 128 + ks * 32 + kg * 8;
            short8_t bh = *(const short8_t*)(&Whi[wo]);
            short8_t bl = *(const short8_t*)(&Wlo[wo]);
            acc[ct] = __builtin_amdgcn_mfma_f32_16x16x32_bf16(ah, bh, acc[ct], 0, 0, 0);
            acc[ct] = __builtin_amdgcn_mfma_f32_16x16x32_bf16(al, bh, acc[ct], 0, 0, 0);
            acc[ct] = __builtin_amdgcn_mfma_f32_16x16x32_bf16(ah, bl, acc[ct], 0, 0, 0);
        }
    }

    // epilogue: C/D layout col=lane&15, row=(lane>>4)*4+reg  [m89-verified]
    const int orow0 = row0 + w * 16 + kg * 4;
#pragma unroll
    for (int ct = 0; ct < CT; ++ct) {
        float b = (bias != nullptr) ? bias[ct * 16 + col] : 0.f;
#pragma unroll
        for (int j = 0; j < 4; ++j) {
            int r = orow0 + j;
            if (r < n) C[(size_t)r * NC + ct * 16 + col] = acc[ct][j] + b;
        }
    }
}

// ---------------- SpMM mean-aggregate + bias + optional relu ----------------

__global__ __launch_bounds__(256) void spmm_k(const float* __restrict__ t,
                                              const int* __restrict__ row_ptr,
                                              const int* __restrict__ csr_col,
                                              const float* __restrict__ deg_inv,
                                              const float* __restrict__ bias,
                                              float* __restrict__ out, int n, int do_relu) {
    int wave = threadIdx.x >> 6;
    int lane = threadIdx.x & 63;
    int row = blockIdx.x * 4 + wave;
    if (row >= n) return;

    const float2* t2 = (const float2*)t;
    float2 acc = t2[(size_t)row * 64 + lane];  // self loop
    int s = row_ptr[row], e = row_ptr[row + 1];
    int p = s;
    for (; p + 1 < e; p += 2) {
        int c0 = csr_col[p];
        int c1 = csr_col[p + 1];
        float2 v0 = t2[(size_t)c0 * 64 + lane];
        float2 v1 = t2[(size_t)c1 * 64 + lane];
        acc.x += v0.x + v1.x;
        acc.y += v0.y + v1.y;
    }
    if (p < e) {
        int c = csr_col[p];
        float2 v = t2[(size_t)c * 64 + lane];
        acc.x += v.x;
        acc.y += v.y;
    }
    float di = deg_inv[row];
    float2 b = ((const float2*)bias)[lane];
    float rx = fmaf(acc.x, di, b.x);
    float ry = fmaf(acc.y, di, b.y);
    if (do_relu) { rx = fmaxf(rx, 0.f); ry = fmaxf(ry, 0.f); }
    ((float2*)out)[(size_t)row * 64 + lane] = make_float2(rx, ry);
}

// ---------------- launch ----------------

extern "C" void kernel_launch(void* const* d_in, const int* in_sizes, int n_in,
                              void* d_out, int out_size, void* d_ws, size_t ws_size,
                              hipStream_t stream) {
    const float* x  = (const float*)d_in[0];
    const int* edges = (const int*)d_in[1];
    const float* W1 = (const float*)d_in[2];
    const float* b1 = (const float*)d_in[3];
    const float* W2 = (const float*)d_in[4];
    const float* b2 = (const float*)d_in[5];
    const float* W3 = (const float*)d_in[6];
    const float* b3 = (const float*)d_in[7];
    const float* W4 = (const float*)d_in[8];
    const float* b4 = (const float*)d_in[9];

    const int N = in_sizes[0] / 128;
    const int E = in_sizes[1] / 2;
    const int* e_row = edges;
    const int* e_col = edges + E;

    char* p = (char*)d_ws;
    auto alloc = [&](size_t bytes) {
        void* r = (void*)p;
        p += (bytes + 255) & ~(size_t)255;
        return r;
    };
    float* t_buf   = (float*)alloc((size_t)N * 128 * 4);
    float* h_buf   = (float*)alloc((size_t)N * 128 * 4);
    int*   deg     = (int*)alloc((size_t)N * 4);
    float* deginv  = (float*)alloc((size_t)N * 4);
    int*   row_ptr = (int*)alloc((size_t)(N + 1) * 4);
    int*   fillc   = (int*)alloc((size_t)N * 4);
    int*   csr_col = (int*)alloc((size_t)E * 4);
    unsigned short* w1h = (unsigned short*)alloc(128 * 128 * 2);
    unsigned short* w1l = (unsigned short*)alloc(128 * 128 * 2);
    unsigned short* w2h = (unsigned short*)alloc(128 * 128 * 2);
    unsigned short* w2l = (unsigned short*)alloc(128 * 128 * 2);
    unsigned short* wfh = (unsigned short*)alloc(64 * 128 * 2);
    unsigned short* wfl = (unsigned short*)alloc(64 * 128 * 2);
    float* bfv     = (float*)alloc(64 * 4);
    int*   blksums = (int*)alloc(4096 * 4);

    float* out = (float*)d_out;

    hipMemsetAsync(deg, 0, (size_t)N * 4, stream);
    hipMemsetAsync(fillc, 0, (size_t)N * 4, stream);

    const int nb = (N + SCAN_BLOCK - 1) / SCAN_BLOCK;

    count_deg_k<<<(E + 255) / 256, 256, 0, stream>>>(e_row, E, deg);
    block_sum_k<<<nb, SCAN_BLOCK, 0, stream>>>(deg, N, blksums);
    scan_blk_sums_k<<<1, 64, 0, stream>>>(blksums, nb, row_ptr, N, E);
    scan_phase3_k<<<nb, SCAN_BLOCK, 0, stream>>>(deg, N, blksums, row_ptr);
    fill_csr_k<<<(E + 255) / 256, 256, 0, stream>>>(e_row, e_col, E, row_ptr, fillc, csr_col);
    deg_inv_k<<<(N + 255) / 256, 256, 0, stream>>>(deg, deginv, N);

    split_w_k<<<(128 * 128 + 255) / 256, 256, 0, stream>>>(W1, 128, w1h, w1l);
    split_w_k<<<(128 * 128 + 255) / 256, 256, 0, stream>>>(W2, 128, w2h, w2l);
    fuse_w34_k<<<(128 * 64 + 64 + 255) / 256, 256, 0, stream>>>(W3, b3, W4, b4, wfh, wfl, bfv);

    const int gblocks = (N + 63) / 64;

    // layer 1: t1 = x @ W1 ; h1 = relu(D^-1 A t1 + b1)
    gemm_mfma_k<128><<<gblocks, 256, 0, stream>>>(x, w1h, w1l, nullptr, t_buf, N);
    spmm_k<<<(N + 3) / 4, 256, 0, stream>>>(t_buf, row_ptr, csr_col, deginv, b1, h_buf, N, 1);

    // layer 2
    gemm_mfma_k<128><<<gblocks, 256, 0, stream>>>(h_buf, w2h, w2l, nullptr, t_buf, N);
    spmm_k<<<(N + 3) / 4, 256, 0, stream>>>(t_buf, row_ptr, csr_col, deginv, b2, h_buf, N, 1);

    // post_mp fused: out = h2 @ (W3@W4) + (b3@W4+b4)
    gemm_mfma_k<64><<<gblocks, 256, 0, stream>>>(h_buf, wfh, wfl, bfv, out, N);
}

// Round 3
// 331.968 us; speedup vs baseline: 1.3889x; 1.2759x over previous
//
#include <hip/hip_runtime.h>
#include <hip/hip_bf16.h>

#define SCAN_BLOCK 512

typedef __attribute__((ext_vector_type(8))) short short8_t;
typedef __attribute__((ext_vector_type(4))) float f32x4;

__device__ inline unsigned short bf16_rne(float f) {
    union { float f; unsigned u; } x; x.f = f;
    unsigned r = x.u + 0x7fffu + ((x.u >> 16) & 1u);
    return (unsigned short)(r >> 16);
}
__device__ inline float bf16_to_f32(unsigned short h) {
    union { unsigned u; float f; } x; x.u = ((unsigned)h) << 16;
    return x.f;
}

// ---------------- CSR build ----------------

__global__ void count_deg_k(const int* __restrict__ e_row, int E, int* __restrict__ deg) {
    int i = blockIdx.x * 256 + threadIdx.x;
    if (i < E) atomicAdd(&deg[e_row[i]], 1);
}

__global__ void block_sum_k(const int* __restrict__ deg, int n, int* __restrict__ blk_sums) {
    __shared__ int s[SCAN_BLOCK];
    int i = blockIdx.x * SCAN_BLOCK + threadIdx.x;
    s[threadIdx.x] = (i < n) ? deg[i] : 0;
    __syncthreads();
    for (int off = SCAN_BLOCK / 2; off > 0; off >>= 1) {
        if (threadIdx.x < off) s[threadIdx.x] += s[threadIdx.x + off];
        __syncthreads();
    }
    if (threadIdx.x == 0) blk_sums[blockIdx.x] = s[0];
}

__global__ void scan_blk_sums_k(int* __restrict__ blk_sums, int nb, int* __restrict__ row_ptr,
                                int n, int E) {
    if (threadIdx.x == 0 && blockIdx.x == 0) {
        int acc = 0;
        for (int b = 0; b < nb; ++b) { int v = blk_sums[b]; blk_sums[b] = acc; acc += v; }
        row_ptr[n] = E;
    }
}

__global__ void scan_phase3_k(const int* __restrict__ deg, int n,
                              const int* __restrict__ blk_sums, int* __restrict__ row_ptr) {
    __shared__ int s[SCAN_BLOCK];
    int i = blockIdx.x * SCAN_BLOCK + threadIdx.x;
    int v = (i < n) ? deg[i] : 0;
    s[threadIdx.x] = v;
    __syncthreads();
    for (int off = 1; off < SCAN_BLOCK; off <<= 1) {
        int t = (threadIdx.x >= (unsigned)off) ? s[threadIdx.x - off] : 0;
        __syncthreads();
        s[threadIdx.x] += t;
        __syncthreads();
    }
    if (i < n) row_ptr[i] = blk_sums[blockIdx.x] + s[threadIdx.x] - v;  // exclusive
}

__global__ void fill_csr_k(const int* __restrict__ e_row, const int* __restrict__ e_col, int E,
                           const int* __restrict__ row_ptr, int* __restrict__ fill_cnt,
                           int* __restrict__ csr_col) {
    int i = blockIdx.x * 256 + threadIdx.x;
    if (i < E) {
        int r = e_row[i];
        int p = row_ptr[r] + atomicAdd(&fill_cnt[r], 1);
        csr_col[p] = e_col[i];
    }
}

__global__ void deg_inv_k(const int* __restrict__ deg, float* __restrict__ deg_inv, int n) {
    int i = blockIdx.x * 256 + threadIdx.x;
    if (i < n) deg_inv[i] = 1.0f / (float)(deg[i] + 1);  // +1 self loop
}

// ---------------- prep: f32 -> bf16 conversions ----------------

// x [n*128] f32 -> bf16, vectorized 4/thread
__global__ void cvt_bf16_k(const float* __restrict__ in, unsigned short* __restrict__ o, int n4) {
    int i = blockIdx.x * 256 + threadIdx.x;
    if (i < n4) {
        float4 v = ((const float4*)in)[i];
        unsigned short r0 = bf16_rne(v.x), r1 = bf16_rne(v.y), r2 = bf16_rne(v.z), r3 = bf16_rne(v.w);
        unsigned lo = (unsigned)r0 | ((unsigned)r1 << 16);
        unsigned hi = (unsigned)r2 | ((unsigned)r3 << 16);
        ((uint2*)o)[i] = make_uint2(lo, hi);
    }
}

// W [128][NC] f32 -> Wt [NC][128] bf16
__global__ void prep_w_k(const float* __restrict__ W, int NC, unsigned short* __restrict__ Wt) {
    int idx = blockIdx.x * 256 + threadIdx.x;
    if (idx < 128 * NC) {
        int k = idx / NC, c = idx % NC;
        Wt[c * 128 + k] = bf16_rne(W[idx]);
    }
}

// fuse W3@W4 (+ b3@W4+b4) -> Wft [64][128] bf16, bfv [64] f32
__global__ void fuse_w34_k(const float* __restrict__ W3, const float* __restrict__ b3,
                           const float* __restrict__ W4, const float* __restrict__ b4,
                           unsigned short* __restrict__ Wft, float* __restrict__ bfv) {
    int idx = blockIdx.x * 256 + threadIdx.x;
    if (idx < 128 * 64) {
        int k = idx >> 6, o = idx & 63;
        float acc = 0.f;
        for (int m = 0; m < 128; ++m) acc = fmaf(W3[k * 128 + m], W4[m * 64 + o], acc);
        Wft[o * 128 + k] = bf16_rne(acc);
    } else if (idx < 128 * 64 + 64) {
        int o = idx - 128 * 64;
        float acc = b4[o];
        for (int m = 0; m < 128; ++m) acc = fmaf(b3[m], W4[m * 64 + o], acc);
        bfv[o] = acc;
    }
}

// ---------------- GEMM: C[n,NC] = A[n,128](bf16) @ Wt[NC,128]^T (+bias) ----------------
// A staged via global_load_lds with pre-swizzled source; XOR swizzle (row&7)<<4 on read
// makes ds_read_b128 conflict-free. 1 MFMA (16x16x32 bf16) per tile.

template <int NC, bool OUT_BF16>
__global__ __launch_bounds__(256) void gemm_bf16_k(const unsigned short* __restrict__ A,
                                                   const unsigned short* __restrict__ Wt,
                                                   const float* __restrict__ bias,
                                                   void* __restrict__ Cout, int n) {
    constexpr int CT = NC / 16;
    __shared__ unsigned short As[64 * 128];  // 16 KiB, linear dest
    const int t = threadIdx.x;
    const int row0 = blockIdx.x * 64;

    // stage 64x128 bf16 tile (A is padded to a multiple of 64 rows)
    {
        const char* Ab = (const char*)(A + (size_t)row0 * 128);
#pragma unroll
        for (int it = 0; it < 4; ++it) {
            int dst = it * 4096 + t * 16;  // linear LDS byte offset (lane-stride 16)
            int rl = dst >> 8;             // local row (256 B per row)
            int off = dst & 255;
            int src = rl * 256 + (off ^ ((rl & 7) << 4));  // inverse-swizzled source
            __builtin_amdgcn_global_load_lds(
                (const __attribute__((address_space(1))) void*)(Ab + src),
                (__attribute__((address_space(3))) void*)((char*)As + dst), 16, 0, 0);
        }
    }
    __syncthreads();

    const int w = t >> 6;
    const int l = t & 63;
    const int col = l & 15;
    const int kg = l >> 4;
    const int arow = w * 16 + col;  // this lane's A-fragment row
    const int abase = arow * 256;
    const int axor = (arow & 7) << 4;

    // hoist the 4 A-fragments (K = 4 x 32)
    short8_t afrag[4];
#pragma unroll
    for (int ks = 0; ks < 4; ++ks) {
        int abyte = abase + ((ks * 64 + kg * 16) ^ axor);
        afrag[ks] = *(const short8_t*)((const char*)As + abyte);
    }

    f32x4 acc[CT];
#pragma unroll
    for (int ct = 0; ct < CT; ++ct) acc[ct] = (f32x4){0.f, 0.f, 0.f, 0.f};

#pragma unroll
    for (int ct = 0; ct < CT; ++ct) {
        const unsigned short* wp = Wt + (size_t)(ct * 16 + col) * 128 + kg * 8;
#pragma unroll
        for (int ks = 0; ks < 4; ++ks) {
            short8_t b = *(const short8_t*)(wp + ks * 32);
            acc[ct] = __builtin_amdgcn_mfma_f32_16x16x32_bf16(afrag[ks], b, acc[ct], 0, 0, 0);
        }
    }

    // epilogue: C/D layout col=lane&15, row=(lane>>4)*4+reg
    const int orow0 = row0 + w * 16 + kg * 4;
    if (OUT_BF16) {
        unsigned short* C = (unsigned short*)Cout;  // padded buffer: no row mask needed
#pragma unroll
        for (int ct = 0; ct < CT; ++ct) {
#pragma unroll
            for (int j = 0; j < 4; ++j) {
                C[(size_t)(orow0 + j) * NC + ct * 16 + col] = bf16_rne(acc[ct][j]);
            }
        }
    } else {
        float* C = (float*)Cout;
#pragma unroll
        for (int ct = 0; ct < CT; ++ct) {
            float b = (bias != nullptr) ? bias[ct * 16 + col] : 0.f;
#pragma unroll
            for (int j = 0; j < 4; ++j) {
                int r = orow0 + j;
                if (r < n) C[(size_t)r * NC + ct * 16 + col] = acc[ct][j] + b;
            }
        }
    }
}

// ---------------- SpMM mean-aggregate + bias + relu (bf16 in, bf16 out) ----------------
// out[i,:] = relu( deg_inv[i] * (t[i,:] + sum_nb t[col,:]) + bias )

__global__ __launch_bounds__(256) void spmm_k(const unsigned short* __restrict__ t,
                                              const int* __restrict__ row_ptr,
                                              const int* __restrict__ csr_col,
                                              const float* __restrict__ deg_inv,
                                              const float* __restrict__ bias,
                                              unsigned short* __restrict__ out, int n) {
    int wave = threadIdx.x >> 6;
    int lane = threadIdx.x & 63;
    int row = blockIdx.x * 4 + wave;
    if (row >= n) return;

    const unsigned* tw = (const unsigned*)t;  // 1 uint = 2 bf16 features
    unsigned sv = tw[(size_t)row * 64 + lane];  // self loop
    float ax = bf16_to_f32((unsigned short)(sv & 0xffff));
    float ay = bf16_to_f32((unsigned short)(sv >> 16));

    int s = row_ptr[row], e = row_ptr[row + 1];
    int p = s;
    for (; p + 4 <= e; p += 4) {
        int c0 = csr_col[p + 0];
        int c1 = csr_col[p + 1];
        int c2 = csr_col[p + 2];
        int c3 = csr_col[p + 3];
        unsigned v0 = tw[(size_t)c0 * 64 + lane];
        unsigned v1 = tw[(size_t)c1 * 64 + lane];
        unsigned v2 = tw[(size_t)c2 * 64 + lane];
        unsigned v3 = tw[(size_t)c3 * 64 + lane];
        ax += bf16_to_f32((unsigned short)(v0 & 0xffff)) + bf16_to_f32((unsigned short)(v1 & 0xffff)) +
              bf16_to_f32((unsigned short)(v2 & 0xffff)) + bf16_to_f32((unsigned short)(v3 & 0xffff));
        ay += bf16_to_f32((unsigned short)(v0 >> 16)) + bf16_to_f32((unsigned short)(v1 >> 16)) +
              bf16_to_f32((unsigned short)(v2 >> 16)) + bf16_to_f32((unsigned short)(v3 >> 16));
    }
    for (; p < e; ++p) {
        int c = csr_col[p];
        unsigned v = tw[(size_t)c * 64 + lane];
        ax += bf16_to_f32((unsigned short)(v & 0xffff));
        ay += bf16_to_f32((unsigned short)(v >> 16));
    }

    float di = deg_inv[row];
    float2 b = ((const float2*)bias)[lane];
    float rx = fmaxf(fmaf(ax, di, b.x), 0.f);
    float ry = fmaxf(fmaf(ay, di, b.y), 0.f);
    unsigned pk = (unsigned)bf16_rne(rx) | ((unsigned)bf16_rne(ry) << 16);
    ((unsigned*)out)[(size_t)row * 64 + lane] = pk;
}

// ---------------- launch ----------------

extern "C" void kernel_launch(void* const* d_in, const int* in_sizes, int n_in,
                              void* d_out, int out_size, void* d_ws, size_t ws_size,
                              hipStream_t stream) {
    const float* x  = (const float*)d_in[0];
    const int* edges = (const int*)d_in[1];
    const float* W1 = (const float*)d_in[2];
    const float* b1 = (const float*)d_in[3];
    const float* W2 = (const float*)d_in[4];
    const float* b2 = (const float*)d_in[5];
    const float* W3 = (const float*)d_in[6];
    const float* b3 = (const float*)d_in[7];
    const float* W4 = (const float*)d_in[8];
    const float* b4 = (const float*)d_in[9];

    const int N = in_sizes[0] / 128;
    const int E = in_sizes[1] / 2;
    const int NPAD = (N + 63) & ~63;  // GEMM blocks read/write whole 64-row tiles
    const int* e_row = edges;
    const int* e_col = edges + E;

    char* p = (char*)d_ws;
    auto alloc = [&](size_t bytes) {
        void* r = (void*)p;
        p += (bytes + 255) & ~(size_t)255;
        return r;
    };
    unsigned short* x_bf = (unsigned short*)alloc((size_t)NPAD * 128 * 2);
    unsigned short* t_bf = (unsigned short*)alloc((size_t)NPAD * 128 * 2);
    unsigned short* h_bf = (unsigned short*)alloc((size_t)NPAD * 128 * 2);
    int*   deg     = (int*)alloc((size_t)N * 4);
    float* deginv  = (float*)alloc((size_t)N * 4);
    int*   row_ptr = (int*)alloc((size_t)(N + 1) * 4);
    int*   fillc   = (int*)alloc((size_t)N * 4);
    int*   csr_col = (int*)alloc((size_t)E * 4);
    unsigned short* w1t = (unsigned short*)alloc(128 * 128 * 2);
    unsigned short* w2t = (unsigned short*)alloc(128 * 128 * 2);
    unsigned short* wft = (unsigned short*)alloc(64 * 128 * 2);
    float* bfv     = (float*)alloc(64 * 4);
    int*   blksums = (int*)alloc(4096 * 4);

    float* out = (float*)d_out;

    hipMemsetAsync(deg, 0, (size_t)N * 4, stream);
    hipMemsetAsync(fillc, 0, (size_t)N * 4, stream);

    const int nb = (N + SCAN_BLOCK - 1) / SCAN_BLOCK;

    count_deg_k<<<(E + 255) / 256, 256, 0, stream>>>(e_row, E, deg);
    block_sum_k<<<nb, SCAN_BLOCK, 0, stream>>>(deg, N, blksums);
    scan_blk_sums_k<<<1, 64, 0, stream>>>(blksums, nb, row_ptr, N, E);
    scan_phase3_k<<<nb, SCAN_BLOCK, 0, stream>>>(deg, N, blksums, row_ptr);
    fill_csr_k<<<(E + 255) / 256, 256, 0, stream>>>(e_row, e_col, E, row_ptr, fillc, csr_col);
    deg_inv_k<<<(N + 255) / 256, 256, 0, stream>>>(deg, deginv, N);

    cvt_bf16_k<<<(N * 32 + 255) / 256, 256, 0, stream>>>(x, x_bf, N * 32);
    prep_w_k<<<64, 256, 0, stream>>>(W1, 128, w1t);
    prep_w_k<<<64, 256, 0, stream>>>(W2, 128, w2t);
    fuse_w34_k<<<(128 * 64 + 64 + 255) / 256, 256, 0, stream>>>(W3, b3, W4, b4, wft, bfv);

    const int gblocks = NPAD / 64;

    // layer 1: t1 = x @ W1 ; h1 = relu(D^-1 A t1 + b1)
    gemm_bf16_k<128, true><<<gblocks, 256, 0, stream>>>(x_bf, w1t, nullptr, t_bf, N);
    spmm_k<<<(N + 3) / 4, 256, 0, stream>>>(t_bf, row_ptr, csr_col, deginv, b1, h_bf, N);

    // layer 2
    gemm_bf16_k<128, true><<<gblocks, 256, 0, stream>>>(h_bf, w2t, nullptr, t_bf, N);
    spmm_k<<<(N + 3) / 4, 256, 0, stream>>>(t_bf, row_ptr, csr_col, deginv, b2, h_bf, N);

    // post_mp fused: out = h2 @ (W3@W4) + (b3@W4+b4)
    gemm_bf16_k<64, false><<<gblocks, 256, 0, stream>>>(h_bf, wft, bfv, out, N);
}

// Round 4
// 306.697 us; speedup vs baseline: 1.5034x; 1.0824x over previous
//
#include <hip/hip_runtime.h>
#include <hip/hip_bf16.h>

#define SCAN_BLOCK 512

typedef __attribute__((ext_vector_type(8))) short short8_t;
typedef __attribute__((ext_vector_type(8))) unsigned short ushort8_t;
typedef __attribute__((ext_vector_type(4))) float f32x4;

__device__ inline unsigned short bf16_rne(float f) {
    union { float f; unsigned u; } x; x.f = f;
    unsigned r = x.u + 0x7fffu + ((x.u >> 16) & 1u);
    return (unsigned short)(r >> 16);
}
__device__ inline float bf16_to_f32(unsigned short h) {
    union { unsigned u; float f; } x; x.u = ((unsigned)h) << 16;
    return x.f;
}

// ---------------- CSR build ----------------

__global__ void count_deg_k(const int* __restrict__ e_row, int E, int* __restrict__ deg) {
    int i = blockIdx.x * 256 + threadIdx.x;
    if (i < E) atomicAdd(&deg[e_row[i]], 1);
}

__global__ void block_sum_k(const int* __restrict__ deg, int n, int* __restrict__ blk_sums) {
    __shared__ int s[SCAN_BLOCK];
    int i = blockIdx.x * SCAN_BLOCK + threadIdx.x;
    s[threadIdx.x] = (i < n) ? deg[i] : 0;
    __syncthreads();
    for (int off = SCAN_BLOCK / 2; off > 0; off >>= 1) {
        if (threadIdx.x < off) s[threadIdx.x] += s[threadIdx.x + off];
        __syncthreads();
    }
    if (threadIdx.x == 0) blk_sums[blockIdx.x] = s[0];
}

// phase3 merged: per-block prefix of blk_sums computed in-kernel (nb <= ~100),
// writes row_ptr, cursor (fill_csr scratch), deg_inv, and row_ptr[n].
__global__ void scan_phase3_k(const int* __restrict__ deg, int n,
                              const int* __restrict__ blk_sums,
                              int* __restrict__ row_ptr, int* __restrict__ cursor,
                              float* __restrict__ deginv) {
    __shared__ int s[SCAN_BLOCK];
    __shared__ int prefix_s;
    const int bid = blockIdx.x;
    if (threadIdx.x < 64) {
        int acc = 0;
        for (int j = threadIdx.x; j < bid; j += 64) acc += blk_sums[j];
#pragma unroll
        for (int off = 32; off > 0; off >>= 1) acc += __shfl_down(acc, off);
        if (threadIdx.x == 0) prefix_s = acc;
    }
    int i = bid * SCAN_BLOCK + threadIdx.x;
    int v = (i < n) ? deg[i] : 0;
    s[threadIdx.x] = v;
    __syncthreads();
    for (int off = 1; off < SCAN_BLOCK; off <<= 1) {
        int t = (threadIdx.x >= (unsigned)off) ? s[threadIdx.x - off] : 0;
        __syncthreads();
        s[threadIdx.x] += t;
        __syncthreads();
    }
    if (i < n) {
        int rp = prefix_s + s[threadIdx.x] - v;  // exclusive
        row_ptr[i] = rp;
        cursor[i] = rp;
        deginv[i] = 1.0f / (float)(v + 1);  // +1 self loop
        if (i == n - 1) row_ptr[n] = prefix_s + s[threadIdx.x];
    }
}

__global__ void fill_csr_k(const int* __restrict__ e_row, const int* __restrict__ e_col, int E,
                           int* __restrict__ cursor, int* __restrict__ csr_col) {
    int i = blockIdx.x * 256 + threadIdx.x;
    if (i < E) {
        int p = atomicAdd(&cursor[e_row[i]], 1);
        csr_col[p] = e_col[i];
    }
}

// ---------------- merged weight prep ----------------
// [0,16384): W1 -> w1t transposed bf16; [16384,32768): W2 -> w2t;
// [32768,40960): Wf = W3@W4 -> wft transposed bf16; [40960,41024): bfv = b3@W4+b4

__global__ void prep_weights_k(const float* __restrict__ W1, const float* __restrict__ W2,
                               const float* __restrict__ W3, const float* __restrict__ b3,
                               const float* __restrict__ W4, const float* __restrict__ b4,
                               unsigned short* __restrict__ w1t, unsigned short* __restrict__ w2t,
                               unsigned short* __restrict__ wft, float* __restrict__ bfv) {
    int idx = blockIdx.x * 256 + threadIdx.x;
    if (idx < 16384) {
        int k = idx >> 7, c = idx & 127;
        w1t[c * 128 + k] = bf16_rne(W1[idx]);
    } else if (idx < 32768) {
        int j = idx - 16384;
        int k = j >> 7, c = j & 127;
        w2t[c * 128 + k] = bf16_rne(W2[j]);
    } else if (idx < 40960) {
        int j = idx - 32768;
        int k = j >> 6, o = j & 63;
        float acc = 0.f;
        for (int m = 0; m < 128; ++m) acc = fmaf(W3[k * 128 + m], W4[m * 64 + o], acc);
        wft[o * 128 + k] = bf16_rne(acc);
    } else if (idx < 41024) {
        int o = idx - 40960;
        float acc = b4[o];
        for (int m = 0; m < 128; ++m) acc = fmaf(b3[m], W4[m * 64 + o], acc);
        bfv[o] = acc;
    }
}

// ---------------- GEMM: C[n,NC] = A[n,128] @ Wt[NC,128]^T (+bias) ----------------
// bf16-input path: global_load_lds w/ pre-swizzled source; f32-input path: reg-stage,
// convert, ds_write swizzled. XOR swizzle (row&7)<<4 => conflict-free ds_read_b128.

template <int NC, bool OUT_BF16, bool IN_F32>
__global__ __launch_bounds__(256) void gemm_bf16_k(const void* __restrict__ Ain,
                                                   const unsigned short* __restrict__ Wt,
                                                   const float* __restrict__ bias,
                                                   void* __restrict__ Cout, int n) {
    constexpr int CT = NC / 16;
    __shared__ unsigned short As[64 * 128];  // 16 KiB
    const int t = threadIdx.x;
    const int row0 = blockIdx.x * 64;

    if (IN_F32) {
        const float* A = (const float*)Ain;
#pragma unroll
        for (int it = 0; it < 4; ++it) {
            int idx = it * 2048 + t * 8;
            int rl = idx >> 7;
            int cl = idx & 127;
            int gr = row0 + rl; if (gr > n - 1) gr = n - 1;
            const float4* src = (const float4*)(A + (size_t)gr * 128 + cl);
            float4 v0 = src[0];
            float4 v1 = src[1];
            float f[8] = {v0.x, v0.y, v0.z, v0.w, v1.x, v1.y, v1.z, v1.w};
            ushort8_t vh;
#pragma unroll
            for (int j = 0; j < 8; ++j) vh[j] = bf16_rne(f[j]);
            int byte = rl * 256 + ((cl * 2) ^ ((rl & 7) << 4));
            *(ushort8_t*)((char*)As + byte) = vh;
        }
    } else {
        const char* Ab = (const char*)((const unsigned short*)Ain + (size_t)row0 * 128);
#pragma unroll
        for (int it = 0; it < 4; ++it) {
            int dst = it * 4096 + t * 16;
            int rl = dst >> 8;
            int off = dst & 255;
            int src = rl * 256 + (off ^ ((rl & 7) << 4));  // inverse-swizzled source
            __builtin_amdgcn_global_load_lds(
                (const __attribute__((address_space(1))) void*)(Ab + src),
                (__attribute__((address_space(3))) void*)((char*)As + dst), 16, 0, 0);
        }
    }
    __syncthreads();

    const int w = t >> 6;
    const int l = t & 63;
    const int col = l & 15;
    const int kg = l >> 4;
    const int arow = w * 16 + col;
    const int abase = arow * 256;
    const int axor = (arow & 7) << 4;

    short8_t afrag[4];
#pragma unroll
    for (int ks = 0; ks < 4; ++ks) {
        int abyte = abase + ((ks * 64 + kg * 16) ^ axor);
        afrag[ks] = *(const short8_t*)((const char*)As + abyte);
    }

    f32x4 acc[CT];
#pragma unroll
    for (int ct = 0; ct < CT; ++ct) acc[ct] = (f32x4){0.f, 0.f, 0.f, 0.f};

#pragma unroll
    for (int ct = 0; ct < CT; ++ct) {
        const unsigned short* wp = Wt + (size_t)(ct * 16 + col) * 128 + kg * 8;
#pragma unroll
        for (int ks = 0; ks < 4; ++ks) {
            short8_t b = *(const short8_t*)(wp + ks * 32);
            acc[ct] = __builtin_amdgcn_mfma_f32_16x16x32_bf16(afrag[ks], b, acc[ct], 0, 0, 0);
        }
    }

    // epilogue: C/D layout col=lane&15, row=(lane>>4)*4+reg
    const int orow0 = row0 + w * 16 + kg * 4;
    if (OUT_BF16) {
        unsigned short* C = (unsigned short*)Cout;  // padded: no row mask
#pragma unroll
        for (int ct = 0; ct < CT; ++ct) {
#pragma unroll
            for (int j = 0; j < 4; ++j) {
                C[(size_t)(orow0 + j) * NC + ct * 16 + col] = bf16_rne(acc[ct][j]);
            }
        }
    } else {
        float* C = (float*)Cout;
#pragma unroll
        for (int ct = 0; ct < CT; ++ct) {
            float b = (bias != nullptr) ? bias[ct * 16 + col] : 0.f;
#pragma unroll
            for (int j = 0; j < 4; ++j) {
                int r = orow0 + j;
                if (r < n) C[(size_t)r * NC + ct * 16 + col] = acc[ct][j] + b;
            }
        }
    }
}

// ---------------- SpMM mean-aggregate + bias + relu (bf16 in/out) ----------------
// 2 rows per wave: 32 lanes/row, uint2 (4 bf16) per lane = 256 B per gathered row.

__global__ __launch_bounds__(256) void spmm_k(const unsigned short* __restrict__ t,
                                              const int* __restrict__ row_ptr,
                                              const int* __restrict__ csr_col,
                                              const float* __restrict__ deg_inv,
                                              const float* __restrict__ bias,
                                              unsigned short* __restrict__ out, int n) {
    int wave = threadIdx.x >> 6;
    int lane = threadIdx.x & 63;
    int half = lane >> 5;
    int sl = lane & 31;
    int row = blockIdx.x * 8 + wave * 2 + half;
    if (row >= n) return;

    const uint2* tw = (const uint2*)t;
    uint2 sv = tw[(size_t)row * 32 + sl];  // self loop
    float a0 = bf16_to_f32((unsigned short)(sv.x & 0xffff));
    float a1 = bf16_to_f32((unsigned short)(sv.x >> 16));
    float a2 = bf16_to_f32((unsigned short)(sv.y & 0xffff));
    float a3 = bf16_to_f32((unsigned short)(sv.y >> 16));

    int s = row_ptr[row], e = row_ptr[row + 1];
    int p = s;
    for (; p + 4 <= e; p += 4) {
        int c0 = csr_col[p + 0];
        int c1 = csr_col[p + 1];
        int c2 = csr_col[p + 2];
        int c3 = csr_col[p + 3];
        uint2 v0 = tw[(size_t)c0 * 32 + sl];
        uint2 v1 = tw[(size_t)c1 * 32 + sl];
        uint2 v2 = tw[(size_t)c2 * 32 + sl];
        uint2 v3 = tw[(size_t)c3 * 32 + sl];
        a0 += bf16_to_f32((unsigned short)(v0.x & 0xffff)) + bf16_to_f32((unsigned short)(v1.x & 0xffff)) +
              bf16_to_f32((unsigned short)(v2.x & 0xffff)) + bf16_to_f32((unsigned short)(v3.x & 0xffff));
        a1 += bf16_to_f32((unsigned short)(v0.x >> 16)) + bf16_to_f32((unsigned short)(v1.x >> 16)) +
              bf16_to_f32((unsigned short)(v2.x >> 16)) + bf16_to_f32((unsigned short)(v3.x >> 16));
        a2 += bf16_to_f32((unsigned short)(v0.y & 0xffff)) + bf16_to_f32((unsigned short)(v1.y & 0xffff)) +
              bf16_to_f32((unsigned short)(v2.y & 0xffff)) + bf16_to_f32((unsigned short)(v3.y & 0xffff));
        a3 += bf16_to_f32((unsigned short)(v0.y >> 16)) + bf16_to_f32((unsigned short)(v1.y >> 16)) +
              bf16_to_f32((unsigned short)(v2.y >> 16)) + bf16_to_f32((unsigned short)(v3.y >> 16));
    }
    for (; p < e; ++p) {
        int c = csr_col[p];
        uint2 v = tw[(size_t)c * 32 + sl];
        a0 += bf16_to_f32((unsigned short)(v.x & 0xffff));
        a1 += bf16_to_f32((unsigned short)(v.x >> 16));
        a2 += bf16_to_f32((unsigned short)(v.y & 0xffff));
        a3 += bf16_to_f32((unsigned short)(v.y >> 16));
    }

    float di = deg_inv[row];
    float4 b = ((const float4*)bias)[sl];
    float r0 = fmaxf(fmaf(a0, di, b.x), 0.f);
    float r1 = fmaxf(fmaf(a1, di, b.y), 0.f);
    float r2 = fmaxf(fmaf(a2, di, b.z), 0.f);
    float r3 = fmaxf(fmaf(a3, di, b.w), 0.f);
    uint2 pk;
    pk.x = (unsigned)bf16_rne(r0) | ((unsigned)bf16_rne(r1) << 16);
    pk.y = (unsigned)bf16_rne(r2) | ((unsigned)bf16_rne(r3) << 16);
    ((uint2*)out)[(size_t)row * 32 + sl] = pk;
}

// ---------------- launch ----------------

extern "C" void kernel_launch(void* const* d_in, const int* in_sizes, int n_in,
                              void* d_out, int out_size, void* d_ws, size_t ws_size,
                              hipStream_t stream) {
    const float* x  = (const float*)d_in[0];
    const int* edges = (const int*)d_in[1];
    const float* W1 = (const float*)d_in[2];
    const float* b1 = (const float*)d_in[3];
    const float* W2 = (const float*)d_in[4];
    const float* b2 = (const float*)d_in[5];
    const float* W3 = (const float*)d_in[6];
    const float* b3 = (const float*)d_in[7];
    const float* W4 = (const float*)d_in[8];
    const float* b4 = (const float*)d_in[9];

    const int N = in_sizes[0] / 128;
    const int E = in_sizes[1] / 2;
    const int NPAD = (N + 63) & ~63;
    const int* e_row = edges;
    const int* e_col = edges + E;

    char* p = (char*)d_ws;
    auto alloc = [&](size_t bytes) {
        void* r = (void*)p;
        p += (bytes + 255) & ~(size_t)255;
        return r;
    };
    unsigned short* t_bf = (unsigned short*)alloc((size_t)NPAD * 128 * 2);
    unsigned short* h_bf = (unsigned short*)alloc((size_t)NPAD * 128 * 2);
    int*   deg     = (int*)alloc((size_t)N * 4);
    float* deginv  = (float*)alloc((size_t)N * 4);
    int*   row_ptr = (int*)alloc((size_t)(N + 1) * 4);
    int*   cursor  = (int*)alloc((size_t)N * 4);
    int*   csr_col = (int*)alloc((size_t)E * 4);
    unsigned short* w1t = (unsigned short*)alloc(128 * 128 * 2);
    unsigned short* w2t = (unsigned short*)alloc(128 * 128 * 2);
    unsigned short* wft = (unsigned short*)alloc(64 * 128 * 2);
    float* bfv     = (float*)alloc(64 * 4);
    int*   blksums = (int*)alloc(4096 * 4);

    float* out = (float*)d_out;

    hipMemsetAsync(deg, 0, (size_t)N * 4, stream);

    const int nb = (N + SCAN_BLOCK - 1) / SCAN_BLOCK;

    count_deg_k<<<(E + 255) / 256, 256, 0, stream>>>(e_row, E, deg);
    block_sum_k<<<nb, SCAN_BLOCK, 0, stream>>>(deg, N, blksums);
    scan_phase3_k<<<nb, SCAN_BLOCK, 0, stream>>>(deg, N, blksums, row_ptr, cursor, deginv);
    fill_csr_k<<<(E + 255) / 256, 256, 0, stream>>>(e_row, e_col, E, cursor, csr_col);
    prep_weights_k<<<(41024 + 255) / 256, 256, 0, stream>>>(W1, W2, W3, b3, W4, b4,
                                                            w1t, w2t, wft, bfv);

    const int gblocks = NPAD / 64;

    // layer 1: t1 = x @ W1 (f32 in, converted in-stage) ; h1 = relu(D^-1 A t1 + b1)
    gemm_bf16_k<128, true, true><<<gblocks, 256, 0, stream>>>(x, w1t, nullptr, t_bf, N);
    spmm_k<<<(N + 7) / 8, 256, 0, stream>>>(t_bf, row_ptr, csr_col, deginv, b1, h_bf, N);

    // layer 2
    gemm_bf16_k<128, true, false><<<gblocks, 256, 0, stream>>>(h_bf, w2t, nullptr, t_bf, N);
    spmm_k<<<(N + 7) / 8, 256, 0, stream>>>(t_bf, row_ptr, csr_col, deginv, b2, h_bf, N);

    // post_mp fused: out = h2 @ (W3@W4) + (b3@W4+b4)
    gemm_bf16_k<64, false, false><<<gblocks, 256, 0, stream>>>(h_bf, wft, bfv, out, N);
}

// Round 5
// 248.144 us; speedup vs baseline: 1.8581x; 1.2360x over previous
//
#include <hip/hip_runtime.h>
#include <hip/hip_bf16.h>

#define NB 512  // CSR row-range buckets

typedef __attribute__((ext_vector_type(8))) short short8_t;
typedef __attribute__((ext_vector_type(8))) unsigned short ushort8_t;
typedef __attribute__((ext_vector_type(4))) float f32x4;

__device__ inline unsigned short bf16_rne(float f) {
    union { float f; unsigned u; } x; x.f = f;
    unsigned r = x.u + 0x7fffu + ((x.u >> 16) & 1u);
    return (unsigned short)(r >> 16);
}
__device__ inline float bf16_to_f32(unsigned short h) {
    union { unsigned u; float f; } x; x.u = ((unsigned)h) << 16;
    return x.f;
}

// ---------------- CSR build: two-level counting sort ----------------
// P0: histogram edges into NB row-range buckets (LDS-staged atomics)

__global__ __launch_bounds__(256) void p0_count_k(const int* __restrict__ e_row, int E, int R,
                                                  int* __restrict__ bucket_cnt) {
    __shared__ int h[NB];
    for (int i = threadIdx.x; i < NB; i += 256) h[i] = 0;
    __syncthreads();
    int base = blockIdx.x * 4096;
#pragma unroll
    for (int j = 0; j < 16; ++j) {
        int i = base + j * 256 + threadIdx.x;
        if (i < E) atomicAdd(&h[e_row[i] / R], 1);
    }
    __syncthreads();
    for (int i = threadIdx.x; i < NB; i += 256)
        if (h[i]) atomicAdd(&bucket_cnt[i], h[i]);
}

// P0b: exclusive scan of bucket counts (single block, NB threads)

__global__ void p0b_scan_k(const int* __restrict__ cnt, int* __restrict__ bptr,
                           int* __restrict__ bcur, int E) {
    __shared__ int s[NB];
    int t = threadIdx.x;
    int v = cnt[t];
    s[t] = v;
    __syncthreads();
    for (int off = 1; off < NB; off <<= 1) {
        int u = (t >= off) ? s[t - off] : 0;
        __syncthreads();
        s[t] += u;
        __syncthreads();
    }
    int excl = s[t] - v;
    bptr[t] = excl;
    bcur[t] = excl;
    if (t == NB - 1) bptr[NB] = E;
}

// P1: scatter edges into bucket-ordered packed array (localrow<<16 | col).
// Per-WG LDS histogram -> one atomic run-reservation per bucket -> clustered writes.

__global__ __launch_bounds__(256) void p1_scatter_k(const int* __restrict__ er,
                                                    const int* __restrict__ ec, int E, int R,
                                                    int* __restrict__ bcur,
                                                    unsigned* __restrict__ packed) {
    __shared__ int h[NB];
    __shared__ int base[NB];
    for (int i = threadIdx.x; i < NB; i += 256) h[i] = 0;
    __syncthreads();
    int cb = blockIdx.x * 4096;
    int rows[16], cols[16], bks[16];
#pragma unroll
    for (int j = 0; j < 16; ++j) {
        int i = cb + j * 256 + threadIdx.x;
        if (i < E) {
            int r = er[i];
            rows[j] = r;
            cols[j] = ec[i];
            int b = r / R;
            bks[j] = b;
            atomicAdd(&h[b], 1);
        } else {
            bks[j] = -1;
        }
    }
    __syncthreads();
    for (int i = threadIdx.x; i < NB; i += 256)
        base[i] = h[i] ? atomicAdd(&bcur[i], h[i]) : 0;
    __syncthreads();
    for (int i = threadIdx.x; i < NB; i += 256) h[i] = 0;
    __syncthreads();
#pragma unroll
    for (int j = 0; j < 16; ++j) {
        int b = bks[j];
        if (b >= 0) {
            int off = atomicAdd(&h[b], 1);
            packed[base[b] + off] = ((unsigned)(rows[j] - b * R) << 16) | (unsigned)cols[j];
        }
    }
}

// P2: per bucket: row histogram -> row_ptr/deg_inv, LDS-staged col scatter -> contiguous write.
// Assumes R <= 128 (N=50000, NB=512 -> R=98).

__global__ __launch_bounds__(256) void p2_build_k(const unsigned* __restrict__ packed,
                                                  const int* __restrict__ bptr, int R, int N, int E,
                                                  int* __restrict__ row_ptr,
                                                  float* __restrict__ deginv,
                                                  int* __restrict__ csr_col) {
    __shared__ int hist[128];
    __shared__ int excl[129];
    __shared__ int cur[128];
    __shared__ int lcsr[2048];
    int b = blockIdx.x;
    int s = bptr[b], e = bptr[b + 1];
    int m = e - s;
    for (int i = threadIdx.x; i < 128; i += 256) hist[i] = 0;
    __syncthreads();
    for (int i = threadIdx.x; i < m; i += 256) atomicAdd(&hist[packed[s + i] >> 16], 1);
    __syncthreads();
    if (threadIdx.x == 0) {
        int acc = 0;
        for (int r = 0; r < R; ++r) { excl[r] = acc; acc += hist[r]; }
        excl[R] = acc;
    }
    __syncthreads();
    for (int r = threadIdx.x; r < R; r += 256) {
        int gr = b * R + r;
        if (gr < N) {
            row_ptr[gr] = s + excl[r];
            deginv[gr] = 1.0f / (float)(hist[r] + 1);  // +1 self loop
        }
        cur[r] = excl[r];
    }
    if (b == (int)gridDim.x - 1 && threadIdx.x == 0) row_ptr[N] = E;
    __syncthreads();
    if (m <= 2048) {
        for (int i = threadIdx.x; i < m; i += 256) {
            unsigned pk = packed[s + i];
            int pos = atomicAdd(&cur[pk >> 16], 1);
            lcsr[pos] = (int)(pk & 0xffffu);
        }
        __syncthreads();
        for (int i = threadIdx.x; i < m; i += 256) csr_col[s + i] = lcsr[i];
    } else {  // overflow fallback (effectively unreachable for random data)
        for (int i = threadIdx.x; i < m; i += 256) {
            unsigned pk = packed[s + i];
            int pos = atomicAdd(&cur[pk >> 16], 1);
            csr_col[s + pos] = (int)(pk & 0xffffu);
        }
    }
}

// ---------------- merged weight prep ----------------

__global__ void prep_weights_k(const float* __restrict__ W1, const float* __restrict__ W2,
                               const float* __restrict__ W3, const float* __restrict__ b3,
                               const float* __restrict__ W4, const float* __restrict__ b4,
                               unsigned short* __restrict__ w1t, unsigned short* __restrict__ w2t,
                               unsigned short* __restrict__ wft, float* __restrict__ bfv) {
    int idx = blockIdx.x * 256 + threadIdx.x;
    if (idx < 16384) {
        int k = idx >> 7, c = idx & 127;
        w1t[c * 128 + k] = bf16_rne(W1[idx]);
    } else if (idx < 32768) {
        int j = idx - 16384;
        int k = j >> 7, c = j & 127;
        w2t[c * 128 + k] = bf16_rne(W2[j]);
    } else if (idx < 40960) {
        int j = idx - 32768;
        int k = j >> 6, o = j & 63;
        float acc = 0.f;
        for (int m = 0; m < 128; ++m) acc = fmaf(W3[k * 128 + m], W4[m * 64 + o], acc);
        wft[o * 128 + k] = bf16_rne(acc);
    } else if (idx < 41024) {
        int o = idx - 40960;
        float acc = b4[o];
        for (int m = 0; m < 128; ++m) acc = fmaf(b3[m], W4[m * 64 + o], acc);
        bfv[o] = acc;
    }
}

// ---------------- GEMM: C[n,NC] = A[n,128] @ Wt[NC,128]^T (+bias) ----------------

template <int NC, bool OUT_BF16, bool IN_F32>
__global__ __launch_bounds__(256) void gemm_bf16_k(const void* __restrict__ Ain,
                                                   const unsigned short* __restrict__ Wt,
                                                   const float* __restrict__ bias,
                                                   void* __restrict__ Cout, int n) {
    constexpr int CT = NC / 16;
    __shared__ unsigned short As[64 * 128];  // 16 KiB
    const int t = threadIdx.x;
    const int row0 = blockIdx.x * 64;

    if (IN_F32) {
        const float* A = (const float*)Ain;
#pragma unroll
        for (int it = 0; it < 4; ++it) {
            int idx = it * 2048 + t * 8;
            int rl = idx >> 7;
            int cl = idx & 127;
            int gr = row0 + rl; if (gr > n - 1) gr = n - 1;
            const float4* src = (const float4*)(A + (size_t)gr * 128 + cl);
            float4 v0 = src[0];
            float4 v1 = src[1];
            float f[8] = {v0.x, v0.y, v0.z, v0.w, v1.x, v1.y, v1.z, v1.w};
            ushort8_t vh;
#pragma unroll
            for (int j = 0; j < 8; ++j) vh[j] = bf16_rne(f[j]);
            int byte = rl * 256 + ((cl * 2) ^ ((rl & 7) << 4));
            *(ushort8_t*)((char*)As + byte) = vh;
        }
    } else {
        const char* Ab = (const char*)((const unsigned short*)Ain + (size_t)row0 * 128);
#pragma unroll
        for (int it = 0; it < 4; ++it) {
            int dst = it * 4096 + t * 16;
            int rl = dst >> 8;
            int off = dst & 255;
            int src = rl * 256 + (off ^ ((rl & 7) << 4));  // inverse-swizzled source
            __builtin_amdgcn_global_load_lds(
                (const __attribute__((address_space(1))) void*)(Ab + src),
                (__attribute__((address_space(3))) void*)((char*)As + dst), 16, 0, 0);
        }
    }
    __syncthreads();

    const int w = t >> 6;
    const int l = t & 63;
    const int col = l & 15;
    const int kg = l >> 4;
    const int arow = w * 16 + col;
    const int abase = arow * 256;
    const int axor = (arow & 7) << 4;

    short8_t afrag[4];
#pragma unroll
    for (int ks = 0; ks < 4; ++ks) {
        int abyte = abase + ((ks * 64 + kg * 16) ^ axor);
        afrag[ks] = *(const short8_t*)((const char*)As + abyte);
    }

    f32x4 acc[CT];
#pragma unroll
    for (int ct = 0; ct < CT; ++ct) acc[ct] = (f32x4){0.f, 0.f, 0.f, 0.f};

#pragma unroll
    for (int ct = 0; ct < CT; ++ct) {
        const unsigned short* wp = Wt + (size_t)(ct * 16 + col) * 128 + kg * 8;
#pragma unroll
        for (int ks = 0; ks < 4; ++ks) {
            short8_t b = *(const short8_t*)(wp + ks * 32);
            acc[ct] = __builtin_amdgcn_mfma_f32_16x16x32_bf16(afrag[ks], b, acc[ct], 0, 0, 0);
        }
    }

    const int orow0 = row0 + w * 16 + kg * 4;
    if (OUT_BF16) {
        unsigned short* C = (unsigned short*)Cout;  // padded: no row mask
#pragma unroll
        for (int ct = 0; ct < CT; ++ct) {
#pragma unroll
            for (int j = 0; j < 4; ++j) {
                C[(size_t)(orow0 + j) * NC + ct * 16 + col] = bf16_rne(acc[ct][j]);
            }
        }
    } else {
        float* C = (float*)Cout;
#pragma unroll
        for (int ct = 0; ct < CT; ++ct) {
            float b = (bias != nullptr) ? bias[ct * 16 + col] : 0.f;
#pragma unroll
            for (int j = 0; j < 4; ++j) {
                int r = orow0 + j;
                if (r < n) C[(size_t)r * NC + ct * 16 + col] = acc[ct][j] + b;
            }
        }
    }
}

// ---------------- SpMM mean-aggregate + bias + relu (bf16 in/out) ----------------

__global__ __launch_bounds__(256) void spmm_k(const unsigned short* __restrict__ t,
                                              const int* __restrict__ row_ptr,
                                              const int* __restrict__ csr_col,
                                              const float* __restrict__ deg_inv,
                                              const float* __restrict__ bias,
                                              unsigned short* __restrict__ out, int n) {
    int wave = threadIdx.x >> 6;
    int lane = threadIdx.x & 63;
    int half = lane >> 5;
    int sl = lane & 31;
    int row = blockIdx.x * 8 + wave * 2 + half;
    if (row >= n) return;

    const uint2* tw = (const uint2*)t;
    uint2 sv = tw[(size_t)row * 32 + sl];  // self loop
    float a0 = bf16_to_f32((unsigned short)(sv.x & 0xffff));
    float a1 = bf16_to_f32((unsigned short)(sv.x >> 16));
    float a2 = bf16_to_f32((unsigned short)(sv.y & 0xffff));
    float a3 = bf16_to_f32((unsigned short)(sv.y >> 16));

    int s = row_ptr[row], e = row_ptr[row + 1];
    int p = s;
    for (; p + 4 <= e; p += 4) {
        int c0 = csr_col[p + 0];
        int c1 = csr_col[p + 1];
        int c2 = csr_col[p + 2];
        int c3 = csr_col[p + 3];
        uint2 v0 = tw[(size_t)c0 * 32 + sl];
        uint2 v1 = tw[(size_t)c1 * 32 + sl];
        uint2 v2 = tw[(size_t)c2 * 32 + sl];
        uint2 v3 = tw[(size_t)c3 * 32 + sl];
        a0 += bf16_to_f32((unsigned short)(v0.x & 0xffff)) + bf16_to_f32((unsigned short)(v1.x & 0xffff)) +
              bf16_to_f32((unsigned short)(v2.x & 0xffff)) + bf16_to_f32((unsigned short)(v3.x & 0xffff));
        a1 += bf16_to_f32((unsigned short)(v0.x >> 16)) + bf16_to_f32((unsigned short)(v1.x >> 16)) +
              bf16_to_f32((unsigned short)(v2.x >> 16)) + bf16_to_f32((unsigned short)(v3.x >> 16));
        a2 += bf16_to_f32((unsigned short)(v0.y & 0xffff)) + bf16_to_f32((unsigned short)(v1.y & 0xffff)) +
              bf16_to_f32((unsigned short)(v2.y & 0xffff)) + bf16_to_f32((unsigned short)(v3.y & 0xffff));
        a3 += bf16_to_f32((unsigned short)(v0.y >> 16)) + bf16_to_f32((unsigned short)(v1.y >> 16)) +
              bf16_to_f32((unsigned short)(v2.y >> 16)) + bf16_to_f32((unsigned short)(v3.y >> 16));
    }
    for (; p < e; ++p) {
        int c = csr_col[p];
        uint2 v = tw[(size_t)c * 32 + sl];
        a0 += bf16_to_f32((unsigned short)(v.x & 0xffff));
        a1 += bf16_to_f32((unsigned short)(v.x >> 16));
        a2 += bf16_to_f32((unsigned short)(v.y & 0xffff));
        a3 += bf16_to_f32((unsigned short)(v.y >> 16));
    }

    float di = deg_inv[row];
    float4 b = ((const float4*)bias)[sl];
    float r0 = fmaxf(fmaf(a0, di, b.x), 0.f);
    float r1 = fmaxf(fmaf(a1, di, b.y), 0.f);
    float r2 = fmaxf(fmaf(a2, di, b.z), 0.f);
    float r3 = fmaxf(fmaf(a3, di, b.w), 0.f);
    uint2 pk;
    pk.x = (unsigned)bf16_rne(r0) | ((unsigned)bf16_rne(r1) << 16);
    pk.y = (unsigned)bf16_rne(r2) | ((unsigned)bf16_rne(r3) << 16);
    ((uint2*)out)[(size_t)row * 32 + sl] = pk;
}

// ---------------- launch ----------------

extern "C" void kernel_launch(void* const* d_in, const int* in_sizes, int n_in,
                              void* d_out, int out_size, void* d_ws, size_t ws_size,
                              hipStream_t stream) {
    const float* x  = (const float*)d_in[0];
    const int* edges = (const int*)d_in[1];
    const float* W1 = (const float*)d_in[2];
    const float* b1 = (const float*)d_in[3];
    const float* W2 = (const float*)d_in[4];
    const float* b2 = (const float*)d_in[5];
    const float* W3 = (const float*)d_in[6];
    const float* b3 = (const float*)d_in[7];
    const float* W4 = (const float*)d_in[8];
    const float* b4 = (const float*)d_in[9];

    const int N = in_sizes[0] / 128;
    const int E = in_sizes[1] / 2;
    const int NPAD = (N + 63) & ~63;
    const int R = (N + NB - 1) / NB;  // rows per bucket (98 for N=50000; kernels assume <=128)
    const int* e_row = edges;
    const int* e_col = edges + E;

    char* p = (char*)d_ws;
    auto alloc = [&](size_t bytes) {
        void* r = (void*)p;
        p += (bytes + 255) & ~(size_t)255;
        return r;
    };
    unsigned short* t_bf = (unsigned short*)alloc((size_t)NPAD * 128 * 2);
    unsigned short* h_bf = (unsigned short*)alloc((size_t)NPAD * 128 * 2);
    float* deginv  = (float*)alloc((size_t)N * 4);
    int*   row_ptr = (int*)alloc((size_t)(N + 1) * 4);
    int*   csr_col = (int*)alloc((size_t)E * 4);
    unsigned* packed = (unsigned*)alloc((size_t)E * 4);
    int*   bucket_cnt = (int*)alloc(NB * 4);
    int*   bucket_ptr = (int*)alloc((NB + 1) * 4);
    int*   bucket_cur = (int*)alloc(NB * 4);
    unsigned short* w1t = (unsigned short*)alloc(128 * 128 * 2);
    unsigned short* w2t = (unsigned short*)alloc(128 * 128 * 2);
    unsigned short* wft = (unsigned short*)alloc(64 * 128 * 2);
    float* bfv     = (float*)alloc(64 * 4);

    float* out = (float*)d_out;

    hipMemsetAsync(bucket_cnt, 0, NB * 4, stream);

    const int echunks = (E + 4095) / 4096;
    p0_count_k<<<echunks, 256, 0, stream>>>(e_row, E, R, bucket_cnt);
    p0b_scan_k<<<1, NB, 0, stream>>>(bucket_cnt, bucket_ptr, bucket_cur, E);
    p1_scatter_k<<<echunks, 256, 0, stream>>>(e_row, e_col, E, R, bucket_cur, packed);
    p2_build_k<<<NB, 256, 0, stream>>>(packed, bucket_ptr, R, N, E, row_ptr, deginv, csr_col);
    prep_weights_k<<<(41024 + 255) / 256, 256, 0, stream>>>(W1, W2, W3, b3, W4, b4,
                                                            w1t, w2t, wft, bfv);

    const int gblocks = NPAD / 64;

    // layer 1: t1 = x @ W1 (f32 in, converted in-stage) ; h1 = relu(D^-1 A t1 + b1)
    gemm_bf16_k<128, true, true><<<gblocks, 256, 0, stream>>>(x, w1t, nullptr, t_bf, N);
    spmm_k<<<(N + 7) / 8, 256, 0, stream>>>(t_bf, row_ptr, csr_col, deginv, b1, h_bf, N);

    // layer 2
    gemm_bf16_k<128, true, false><<<gblocks, 256, 0, stream>>>(h_bf, w2t, nullptr, t_bf, N);
    spmm_k<<<(N + 7) / 8, 256, 0, stream>>>(t_bf, row_ptr, csr_col, deginv, b2, h_bf, N);

    // post_mp fused: out = h2 @ (W3@W4) + (b3@W4+b4)
    gemm_bf16_k<64, false, false><<<gblocks, 256, 0, stream>>>(h_bf, wft, bfv, out, N);
}

// Round 6
// 224.021 us; speedup vs baseline: 2.0582x; 1.1077x over previous
//
#include <hip/hip_runtime.h>
#include <hip/hip_bf16.h>

#define NB 512  // CSR row-range buckets

typedef __attribute__((ext_vector_type(8))) short short8_t;
typedef __attribute__((ext_vector_type(8))) unsigned short ushort8_t;
typedef __attribute__((ext_vector_type(4))) float f32x4;

__device__ inline unsigned short bf16_rne(float f) {
    union { float f; unsigned u; } x; x.f = f;
    unsigned r = x.u + 0x7fffu + ((x.u >> 16) & 1u);
    return (unsigned short)(r >> 16);
}
__device__ inline float bf16_to_f32(unsigned short h) {
    union { unsigned u; float f; } x; x.u = ((unsigned)h) << 16;
    return x.f;
}

// ================= 8-wave MFMA GEMM core =================
// As: LDS 64x128 bf16, XOR-swizzled (byte ^= (row&7)<<4 within 256 B row).
// Waves 0-3 -> rows (w&3)*16, col-half 0; waves 4-7 -> col-half 1.

template <int NC, bool OUT_BF16>
__device__ __forceinline__ void gemm_core(const unsigned short* __restrict__ As,
                                          const unsigned short* __restrict__ Wt,
                                          const float* __restrict__ gemm_bias,
                                          void* __restrict__ Cout, int row0, int n) {
    constexpr int CT = NC / 32;  // col tiles per wave
    const int t = threadIdx.x;
    const int w = t >> 6;
    const int l = t & 63;
    const int col = l & 15;
    const int kg = l >> 4;
    const int arow = (w & 3) * 16 + col;
    const int cbase = (w >> 2) * (NC / 2);
    const int abase = arow * 256;
    const int axor = (arow & 7) << 4;

    short8_t afrag[4];
#pragma unroll
    for (int ks = 0; ks < 4; ++ks) {
        int abyte = abase + ((ks * 64 + kg * 16) ^ axor);
        afrag[ks] = *(const short8_t*)((const char*)As + abyte);
    }

    f32x4 acc[CT];
#pragma unroll
    for (int ct = 0; ct < CT; ++ct) acc[ct] = (f32x4){0.f, 0.f, 0.f, 0.f};

#pragma unroll
    for (int ct = 0; ct < CT; ++ct) {
        const unsigned short* wp = Wt + (size_t)(cbase + ct * 16 + col) * 128 + kg * 8;
#pragma unroll
        for (int ks = 0; ks < 4; ++ks) {
            short8_t b = *(const short8_t*)(wp + ks * 32);
            acc[ct] = __builtin_amdgcn_mfma_f32_16x16x32_bf16(afrag[ks], b, acc[ct], 0, 0, 0);
        }
    }

    // C/D layout: col=lane&15, row=(lane>>4)*4+reg
    const int orow0 = row0 + (w & 3) * 16 + kg * 4;
    if (OUT_BF16) {
        unsigned short* C = (unsigned short*)Cout;  // padded buffer: no mask
#pragma unroll
        for (int ct = 0; ct < CT; ++ct) {
#pragma unroll
            for (int j = 0; j < 4; ++j) {
                C[(size_t)(orow0 + j) * NC + cbase + ct * 16 + col] = bf16_rne(acc[ct][j]);
            }
        }
    } else {
        float* C = (float*)Cout;
#pragma unroll
        for (int ct = 0; ct < CT; ++ct) {
            float b = (gemm_bias != nullptr) ? gemm_bias[cbase + ct * 16 + col] : 0.f;
#pragma unroll
            for (int j = 0; j < 4; ++j) {
                int r = orow0 + j;
                if (r < n) C[(size_t)r * NC + cbase + ct * 16 + col] = acc[ct][j] + b;
            }
        }
    }
}

// ================= d1: p0_count (blocks [0,pb)) + weight prep (blocks [pb,pb+wb)) =================

__global__ __launch_bounds__(512) void prep_p0_k(const int* __restrict__ e_row, int E, int R,
                                                 int* __restrict__ bucket_cnt, int pb,
                                                 const float* __restrict__ W1,
                                                 const float* __restrict__ W2,
                                                 const float* __restrict__ W3,
                                                 const float* __restrict__ b3,
                                                 const float* __restrict__ W4,
                                                 const float* __restrict__ b4,
                                                 unsigned short* __restrict__ w1t,
                                                 unsigned short* __restrict__ w2t,
                                                 unsigned short* __restrict__ wft,
                                                 float* __restrict__ bfv) {
    __shared__ int h[NB];
    if ((int)blockIdx.x < pb) {
        for (int i = threadIdx.x; i < NB; i += 512) h[i] = 0;
        __syncthreads();
        int base = blockIdx.x * 8192;
#pragma unroll
        for (int j = 0; j < 16; ++j) {
            int i = base + j * 512 + threadIdx.x;
            if (i < E) atomicAdd(&h[e_row[i] / R], 1);
        }
        __syncthreads();
        for (int i = threadIdx.x; i < NB; i += 512)
            if (h[i]) atomicAdd(&bucket_cnt[i], h[i]);
    } else {
        int idx = (blockIdx.x - pb) * 512 + threadIdx.x;
        if (idx < 16384) {
            int k = idx >> 7, c = idx & 127;
            w1t[c * 128 + k] = bf16_rne(W1[idx]);
        } else if (idx < 32768) {
            int j = idx - 16384;
            int k = j >> 7, c = j & 127;
            w2t[c * 128 + k] = bf16_rne(W2[j]);
        } else if (idx < 40960) {
            int j = idx - 32768;
            int k = j >> 6, o = j & 63;
            float acc = 0.f;
            for (int m = 0; m < 128; ++m) acc = fmaf(W3[k * 128 + m], W4[m * 64 + o], acc);
            wft[o * 128 + k] = bf16_rne(acc);
        } else if (idx < 41024) {
            int o = idx - 40960;
            float acc = b4[o];
            for (int m = 0; m < 128; ++m) acc = fmaf(b3[m], W4[m * 64 + o], acc);
            bfv[o] = acc;
        }
    }
}

// ================= d2: GEMM1 (f32 in) blocks [0,gb) + bucket scan (block gb) =================

__global__ __launch_bounds__(512) void gemm1_p0b_k(const float* __restrict__ x,
                                                   const unsigned short* __restrict__ w1t,
                                                   unsigned short* __restrict__ t1, int n, int gb,
                                                   const int* __restrict__ bucket_cnt,
                                                   int* __restrict__ bptr, int* __restrict__ bcur,
                                                   int E) {
    __shared__ char smem[16384];
    if ((int)blockIdx.x < gb) {
        unsigned short* As = (unsigned short*)smem;
        const int t = threadIdx.x;
        const int row0 = blockIdx.x * 64;
#pragma unroll
        for (int it = 0; it < 2; ++it) {
            int idx = it * 4096 + t * 8;
            int rl = idx >> 7;
            int cl = idx & 127;
            int gr = row0 + rl; if (gr > n - 1) gr = n - 1;
            const float4* src = (const float4*)(x + (size_t)gr * 128 + cl);
            float4 v0 = src[0];
            float4 v1 = src[1];
            float f[8] = {v0.x, v0.y, v0.z, v0.w, v1.x, v1.y, v1.z, v1.w};
            ushort8_t vh;
#pragma unroll
            for (int j = 0; j < 8; ++j) vh[j] = bf16_rne(f[j]);
            int byte = rl * 256 + ((cl * 2) ^ ((rl & 7) << 4));
            *(ushort8_t*)(smem + byte) = vh;
        }
        __syncthreads();
        gemm_core<128, true>(As, w1t, nullptr, t1, row0, n);
    } else {
        int* s = (int*)smem;
        int t = threadIdx.x;  // 512 == NB
        int v = bucket_cnt[t];
        s[t] = v;
        __syncthreads();
        for (int off = 1; off < NB; off <<= 1) {
            int u = (t >= off) ? s[t - off] : 0;
            __syncthreads();
            s[t] += u;
            __syncthreads();
        }
        int excl = s[t] - v;
        bptr[t] = excl;
        bcur[t] = excl;
        if (t == NB - 1) bptr[NB] = E;
    }
}

// ================= P1: bucket-ordered edge scatter (packed localrow<<16|col) =================

__global__ __launch_bounds__(256) void p1_scatter_k(const int* __restrict__ er,
                                                    const int* __restrict__ ec, int E, int R,
                                                    int* __restrict__ bcur,
                                                    unsigned* __restrict__ packed) {
    __shared__ int h[NB];
    __shared__ int base[NB];
    for (int i = threadIdx.x; i < NB; i += 256) h[i] = 0;
    __syncthreads();
    int cb = blockIdx.x * 4096;
    int rows[16], cols[16], bks[16];
#pragma unroll
    for (int j = 0; j < 16; ++j) {
        int i = cb + j * 256 + threadIdx.x;
        if (i < E) {
            int r = er[i];
            rows[j] = r;
            cols[j] = ec[i];
            int b = r / R;
            bks[j] = b;
            atomicAdd(&h[b], 1);
        } else {
            bks[j] = -1;
        }
    }
    __syncthreads();
    for (int i = threadIdx.x; i < NB; i += 256)
        base[i] = h[i] ? atomicAdd(&bcur[i], h[i]) : 0;
    __syncthreads();
    for (int i = threadIdx.x; i < NB; i += 256) h[i] = 0;
    __syncthreads();
#pragma unroll
    for (int j = 0; j < 16; ++j) {
        int b = bks[j];
        if (b >= 0) {
            int off = atomicAdd(&h[b], 1);
            packed[base[b] + off] = ((unsigned)(rows[j] - b * R) << 16) | (unsigned)cols[j];
        }
    }
}

// ================= P2: per-bucket row_ptr/deg_inv + contiguous csr_col =================

__global__ __launch_bounds__(256) void p2_build_k(const unsigned* __restrict__ packed,
                                                  const int* __restrict__ bptr, int R, int N, int E,
                                                  int* __restrict__ row_ptr,
                                                  float* __restrict__ deginv,
                                                  int* __restrict__ csr_col) {
    __shared__ int hist[128];
    __shared__ int excl[129];
    __shared__ int cur[128];
    __shared__ int lcsr[2048];
    int b = blockIdx.x;
    int s = bptr[b], e = bptr[b + 1];
    int m = e - s;
    for (int i = threadIdx.x; i < 128; i += 256) hist[i] = 0;
    __syncthreads();
    for (int i = threadIdx.x; i < m; i += 256) atomicAdd(&hist[packed[s + i] >> 16], 1);
    __syncthreads();
    if (threadIdx.x == 0) {
        int acc = 0;
        for (int r = 0; r < R; ++r) { excl[r] = acc; acc += hist[r]; }
        excl[R] = acc;
    }
    __syncthreads();
    for (int r = threadIdx.x; r < R; r += 256) {
        int gr = b * R + r;
        if (gr < N) {
            row_ptr[gr] = s + excl[r];
            deginv[gr] = 1.0f / (float)(hist[r] + 1);  // +1 self loop
        }
        cur[r] = excl[r];
    }
    if (b == (int)gridDim.x - 1 && threadIdx.x == 0) row_ptr[N] = E;
    __syncthreads();
    if (m <= 2048) {
        for (int i = threadIdx.x; i < m; i += 256) {
            unsigned pk = packed[s + i];
            int pos = atomicAdd(&cur[pk >> 16], 1);
            lcsr[pos] = (int)(pk & 0xffffu);
        }
        __syncthreads();
        for (int i = threadIdx.x; i < m; i += 256) csr_col[s + i] = lcsr[i];
    } else {
        for (int i = threadIdx.x; i < m; i += 256) {
            unsigned pk = packed[s + i];
            int pos = atomicAdd(&cur[pk >> 16], 1);
            csr_col[s + pos] = (int)(pk & 0xffffu);
        }
    }
}

// ================= fused aggregate(+bias+relu) -> LDS -> GEMM =================
// Phase A: 8 waves x 2 rows x 4 iters aggregate 64 rows of tin into swizzled LDS (bf16).
// Phase B: 8-wave MFMA core: Cout = h @ Wt (+gemm_bias).

template <int NC, bool OUT_BF16>
__global__ __launch_bounds__(512) void fused_agg_gemm_k(const unsigned short* __restrict__ tin,
                                                        const int* __restrict__ row_ptr,
                                                        const int* __restrict__ csr_col,
                                                        const float* __restrict__ deginv,
                                                        const float* __restrict__ agg_bias,
                                                        const unsigned short* __restrict__ Wt,
                                                        const float* __restrict__ gemm_bias,
                                                        void* __restrict__ Cout, int n) {
    __shared__ unsigned short As[64 * 128];  // 16 KiB swizzled h-tile
    const int t = threadIdx.x;
    const int row0 = blockIdx.x * 64;
    const int w = t >> 6;
    const int l = t & 63;
    const int half = l >> 5;
    const int sl = l & 31;
    const uint2* tw = (const uint2*)tin;
    const float4 bb = ((const float4*)agg_bias)[sl];

#pragma unroll
    for (int it = 0; it < 4; ++it) {
        int rl = it * 16 + w * 2 + half;
        int row = row0 + rl; if (row > n - 1) row = n - 1;
        uint2 sv = tw[(size_t)row * 32 + sl];  // self loop
        float a0 = bf16_to_f32((unsigned short)(sv.x & 0xffff));
        float a1 = bf16_to_f32((unsigned short)(sv.x >> 16));
        float a2 = bf16_to_f32((unsigned short)(sv.y & 0xffff));
        float a3 = bf16_to_f32((unsigned short)(sv.y >> 16));
        int s = row_ptr[row], e = row_ptr[row + 1];
        int p = s;
        for (; p + 4 <= e; p += 4) {
            int c0 = csr_col[p + 0];
            int c1 = csr_col[p + 1];
            int c2 = csr_col[p + 2];
            int c3 = csr_col[p + 3];
            uint2 v0 = tw[(size_t)c0 * 32 + sl];
            uint2 v1 = tw[(size_t)c1 * 32 + sl];
            uint2 v2 = tw[(size_t)c2 * 32 + sl];
            uint2 v3 = tw[(size_t)c3 * 32 + sl];
            a0 += bf16_to_f32((unsigned short)(v0.x & 0xffff)) + bf16_to_f32((unsigned short)(v1.x & 0xffff)) +
                  bf16_to_f32((unsigned short)(v2.x & 0xffff)) + bf16_to_f32((unsigned short)(v3.x & 0xffff));
            a1 += bf16_to_f32((unsigned short)(v0.x >> 16)) + bf16_to_f32((unsigned short)(v1.x >> 16)) +
                  bf16_to_f32((unsigned short)(v2.x >> 16)) + bf16_to_f32((unsigned short)(v3.x >> 16));
            a2 += bf16_to_f32((unsigned short)(v0.y & 0xffff)) + bf16_to_f32((unsigned short)(v1.y & 0xffff)) +
                  bf16_to_f32((unsigned short)(v2.y & 0xffff)) + bf16_to_f32((unsigned short)(v3.y & 0xffff));
            a3 += bf16_to_f32((unsigned short)(v0.y >> 16)) + bf16_to_f32((unsigned short)(v1.y >> 16)) +
                  bf16_to_f32((unsigned short)(v2.y >> 16)) + bf16_to_f32((unsigned short)(v3.y >> 16));
        }
        for (; p < e; ++p) {
            int c = csr_col[p];
            uint2 v = tw[(size_t)c * 32 + sl];
            a0 += bf16_to_f32((unsigned short)(v.x & 0xffff));
            a1 += bf16_to_f32((unsigned short)(v.x >> 16));
            a2 += bf16_to_f32((unsigned short)(v.y & 0xffff));
            a3 += bf16_to_f32((unsigned short)(v.y >> 16));
        }
        float di = deginv[row];
        float r0 = fmaxf(fmaf(a0, di, bb.x), 0.f);
        float r1 = fmaxf(fmaf(a1, di, bb.y), 0.f);
        float r2 = fmaxf(fmaf(a2, di, bb.z), 0.f);
        float r3 = fmaxf(fmaf(a3, di, bb.w), 0.f);
        uint2 pk;
        pk.x = (unsigned)bf16_rne(r0) | ((unsigned)bf16_rne(r1) << 16);
        pk.y = (unsigned)bf16_rne(r2) | ((unsigned)bf16_rne(r3) << 16);
        int byte = rl * 256 + ((sl * 8) ^ ((rl & 7) << 4));
        *(uint2*)((char*)As + byte) = pk;
    }
    __syncthreads();

    gemm_core<NC, OUT_BF16>(As, Wt, gemm_bias, Cout, row0, n);
}

// ================= launch =================

extern "C" void kernel_launch(void* const* d_in, const int* in_sizes, int n_in,
                              void* d_out, int out_size, void* d_ws, size_t ws_size,
                              hipStream_t stream) {
    const float* x  = (const float*)d_in[0];
    const int* edges = (const int*)d_in[1];
    const float* W1 = (const float*)d_in[2];
    const float* b1 = (const float*)d_in[3];
    const float* W2 = (const float*)d_in[4];
    const float* b2 = (const float*)d_in[5];
    const float* W3 = (const float*)d_in[6];
    const float* b3 = (const float*)d_in[7];
    const float* W4 = (const float*)d_in[8];
    const float* b4 = (const float*)d_in[9];

    const int N = in_sizes[0] / 128;
    const int E = in_sizes[1] / 2;
    const int NPAD = (N + 63) & ~63;
    const int R = (N + NB - 1) / NB;  // rows per bucket (98 for N=50000; kernels assume <=128)
    const int* e_row = edges;
    const int* e_col = edges + E;

    char* p = (char*)d_ws;
    auto alloc = [&](size_t bytes) {
        void* r = (void*)p;
        p += (bytes + 255) & ~(size_t)255;
        return r;
    };
    unsigned short* t_bf = (unsigned short*)alloc((size_t)NPAD * 128 * 2);
    unsigned short* t2_bf = (unsigned short*)alloc((size_t)NPAD * 128 * 2);
    float* deginv  = (float*)alloc((size_t)N * 4);
    int*   row_ptr = (int*)alloc((size_t)(N + 1) * 4);
    int*   csr_col = (int*)alloc((size_t)E * 4);
    unsigned* packed = (unsigned*)alloc((size_t)E * 4);
    int*   bucket_cnt = (int*)alloc(NB * 4);
    int*   bucket_ptr = (int*)alloc((NB + 1) * 4);
    int*   bucket_cur = (int*)alloc(NB * 4);
    unsigned short* w1t = (unsigned short*)alloc(128 * 128 * 2);
    unsigned short* w2t = (unsigned short*)alloc(128 * 128 * 2);
    unsigned short* wft = (unsigned short*)alloc(64 * 128 * 2);
    float* bfv     = (float*)alloc(64 * 4);

    float* out = (float*)d_out;

    hipMemsetAsync(bucket_cnt, 0, NB * 4, stream);

    const int PB = (E + 8191) / 8192;       // p0 blocks (512 thr x 16)
    const int WB = (41024 + 511) / 512;     // weight-prep blocks
    const int gblocks = NPAD / 64;

    // d1: edge bucket histogram + weight prep (independent)
    prep_p0_k<<<PB + WB, 512, 0, stream>>>(e_row, E, R, bucket_cnt, PB,
                                           W1, W2, W3, b3, W4, b4, w1t, w2t, wft, bfv);
    // d2: GEMM1 (t1 = x @ W1) + bucket scan
    gemm1_p0b_k<<<gblocks + 1, 512, 0, stream>>>(x, w1t, t_bf, N, gblocks,
                                                 bucket_cnt, bucket_ptr, bucket_cur, E);
    // d3, d4: CSR build
    p1_scatter_k<<<(E + 4095) / 4096, 256, 0, stream>>>(e_row, e_col, E, R, bucket_cur, packed);
    p2_build_k<<<NB, 256, 0, stream>>>(packed, bucket_ptr, R, N, E, row_ptr, deginv, csr_col);

    // d5: h1 = relu(D^-1 A t1 + b1) -> LDS ; t2 = h1 @ W2 (bf16, padded)
    fused_agg_gemm_k<128, true><<<gblocks, 512, 0, stream>>>(
        t_bf, row_ptr, csr_col, deginv, b1, w2t, nullptr, t2_bf, N);
    // d6: h2 = relu(D^-1 A t2 + b2) -> LDS ; out = h2 @ (W3@W4) + (b3@W4+b4) (f32, masked)
    fused_agg_gemm_k<64, false><<<gblocks, 512, 0, stream>>>(
        t2_bf, row_ptr, csr_col, deginv, b2, wft, bfv, out, N);
}

// Round 7
// 221.338 us; speedup vs baseline: 2.0832x; 1.0121x over previous
//
#include <hip/hip_runtime.h>
#include <hip/hip_bf16.h>

#define NB 512  // CSR row-range buckets

typedef __attribute__((ext_vector_type(8))) short short8_t;
typedef __attribute__((ext_vector_type(8))) unsigned short ushort8_t;
typedef __attribute__((ext_vector_type(4))) float f32x4;

__device__ inline unsigned short bf16_rne(float f) {
    union { float f; unsigned u; } x; x.f = f;
    unsigned r = x.u + 0x7fffu + ((x.u >> 16) & 1u);
    return (unsigned short)(r >> 16);
}
__device__ inline float bf16_to_f32(unsigned short h) {
    union { unsigned u; float f; } x; x.u = ((unsigned)h) << 16;
    return x.f;
}
__device__ __forceinline__ void acc_uint2(float& a0, float& a1, float& a2, float& a3, uint2 v) {
    a0 += bf16_to_f32((unsigned short)(v.x & 0xffff));
    a1 += bf16_to_f32((unsigned short)(v.x >> 16));
    a2 += bf16_to_f32((unsigned short)(v.y & 0xffff));
    a3 += bf16_to_f32((unsigned short)(v.y >> 16));
}

// ================= 8-wave MFMA GEMM core =================
// As: LDS 64x128 bf16, XOR-swizzled (byte ^= (row&7)<<4 within 256 B row).
// Waves 0-3 -> rows (w&3)*16, col-half 0; waves 4-7 -> col-half 1.

template <int NC, bool OUT_BF16>
__device__ __forceinline__ void gemm_core(const unsigned short* __restrict__ As,
                                          const unsigned short* __restrict__ Wt,
                                          const float* __restrict__ gemm_bias,
                                          void* __restrict__ Cout, int row0, int n) {
    constexpr int CT = NC / 32;  // col tiles per wave
    const int t = threadIdx.x;
    const int w = t >> 6;
    const int l = t & 63;
    const int col = l & 15;
    const int kg = l >> 4;
    const int arow = (w & 3) * 16 + col;
    const int cbase = (w >> 2) * (NC / 2);
    const int abase = arow * 256;
    const int axor = (arow & 7) << 4;

    short8_t afrag[4];
#pragma unroll
    for (int ks = 0; ks < 4; ++ks) {
        int abyte = abase + ((ks * 64 + kg * 16) ^ axor);
        afrag[ks] = *(const short8_t*)((const char*)As + abyte);
    }

    f32x4 acc[CT];
#pragma unroll
    for (int ct = 0; ct < CT; ++ct) acc[ct] = (f32x4){0.f, 0.f, 0.f, 0.f};

#pragma unroll
    for (int ct = 0; ct < CT; ++ct) {
        const unsigned short* wp = Wt + (size_t)(cbase + ct * 16 + col) * 128 + kg * 8;
#pragma unroll
        for (int ks = 0; ks < 4; ++ks) {
            short8_t b = *(const short8_t*)(wp + ks * 32);
            acc[ct] = __builtin_amdgcn_mfma_f32_16x16x32_bf16(afrag[ks], b, acc[ct], 0, 0, 0);
        }
    }

    // C/D layout: col=lane&15, row=(lane>>4)*4+reg
    const int orow0 = row0 + (w & 3) * 16 + kg * 4;
    if (OUT_BF16) {
        unsigned short* C = (unsigned short*)Cout;  // padded buffer: no mask
#pragma unroll
        for (int ct = 0; ct < CT; ++ct) {
#pragma unroll
            for (int j = 0; j < 4; ++j) {
                C[(size_t)(orow0 + j) * NC + cbase + ct * 16 + col] = bf16_rne(acc[ct][j]);
            }
        }
    } else {
        float* C = (float*)Cout;
#pragma unroll
        for (int ct = 0; ct < CT; ++ct) {
            float b = (gemm_bias != nullptr) ? gemm_bias[cbase + ct * 16 + col] : 0.f;
#pragma unroll
            for (int j = 0; j < 4; ++j) {
                int r = orow0 + j;
                if (r < n) C[(size_t)r * NC + cbase + ct * 16 + col] = acc[ct][j] + b;
            }
        }
    }
}

// ================= d1: p0_count (blocks [0,pb)) + weight prep (blocks [pb,pb+wb)) =================

__global__ __launch_bounds__(512) void prep_p0_k(const int* __restrict__ e_row, int E, int R,
                                                 int* __restrict__ bucket_cnt, int pb,
                                                 const float* __restrict__ W1,
                                                 const float* __restrict__ W2,
                                                 const float* __restrict__ W3,
                                                 const float* __restrict__ b3,
                                                 const float* __restrict__ W4,
                                                 const float* __restrict__ b4,
                                                 unsigned short* __restrict__ w1t,
                                                 unsigned short* __restrict__ w2t,
                                                 unsigned short* __restrict__ wft,
                                                 float* __restrict__ bfv) {
    __shared__ int h[NB];
    if ((int)blockIdx.x < pb) {
        for (int i = threadIdx.x; i < NB; i += 512) h[i] = 0;
        __syncthreads();
        int base = blockIdx.x * 8192;
#pragma unroll
        for (int j = 0; j < 16; ++j) {
            int i = base + j * 512 + threadIdx.x;
            if (i < E) atomicAdd(&h[e_row[i] / R], 1);
        }
        __syncthreads();
        for (int i = threadIdx.x; i < NB; i += 512)
            if (h[i]) atomicAdd(&bucket_cnt[i], h[i]);
    } else {
        int idx = (blockIdx.x - pb) * 512 + threadIdx.x;
        if (idx < 16384) {
            int k = idx >> 7, c = idx & 127;
            w1t[c * 128 + k] = bf16_rne(W1[idx]);
        } else if (idx < 32768) {
            int j = idx - 16384;
            int k = j >> 7, c = j & 127;
            w2t[c * 128 + k] = bf16_rne(W2[j]);
        } else if (idx < 40960) {
            int j = idx - 32768;
            int k = j >> 6, o = j & 63;
            float acc = 0.f;
            for (int m = 0; m < 128; ++m) acc = fmaf(W3[k * 128 + m], W4[m * 64 + o], acc);
            wft[o * 128 + k] = bf16_rne(acc);
        } else if (idx < 41024) {
            int o = idx - 40960;
            float acc = b4[o];
            for (int m = 0; m < 128; ++m) acc = fmaf(b3[m], W4[m * 64 + o], acc);
            bfv[o] = acc;
        }
    }
}

// ================= d2: GEMM1 (f32 in) blocks [0,gb) + bucket scan (block gb) =================

__global__ __launch_bounds__(512) void gemm1_p0b_k(const float* __restrict__ x,
                                                   const unsigned short* __restrict__ w1t,
                                                   unsigned short* __restrict__ t1, int n, int gb,
                                                   const int* __restrict__ bucket_cnt,
                                                   int* __restrict__ bptr, int* __restrict__ bcur,
                                                   int E) {
    __shared__ char smem[16384];
    if ((int)blockIdx.x < gb) {
        unsigned short* As = (unsigned short*)smem;
        const int t = threadIdx.x;
        const int row0 = blockIdx.x * 64;
#pragma unroll
        for (int it = 0; it < 2; ++it) {
            int idx = it * 4096 + t * 8;
            int rl = idx >> 7;
            int cl = idx & 127;
            int gr = row0 + rl; if (gr > n - 1) gr = n - 1;
            const float4* src = (const float4*)(x + (size_t)gr * 128 + cl);
            float4 v0 = src[0];
            float4 v1 = src[1];
            float f[8] = {v0.x, v0.y, v0.z, v0.w, v1.x, v1.y, v1.z, v1.w};
            ushort8_t vh;
#pragma unroll
            for (int j = 0; j < 8; ++j) vh[j] = bf16_rne(f[j]);
            int byte = rl * 256 + ((cl * 2) ^ ((rl & 7) << 4));
            *(ushort8_t*)(smem + byte) = vh;
        }
        __syncthreads();
        gemm_core<128, true>(As, w1t, nullptr, t1, row0, n);
    } else {
        int* s = (int*)smem;
        int t = threadIdx.x;  // 512 == NB
        int v = bucket_cnt[t];
        s[t] = v;
        __syncthreads();
        for (int off = 1; off < NB; off <<= 1) {
            int u = (t >= off) ? s[t - off] : 0;
            __syncthreads();
            s[t] += u;
            __syncthreads();
        }
        int excl = s[t] - v;
        bptr[t] = excl;
        bcur[t] = excl;
        if (t == NB - 1) bptr[NB] = E;
    }
}

// ================= P1: bucket-ordered edge scatter (packed localrow<<16|col) =================

__global__ __launch_bounds__(256) void p1_scatter_k(const int* __restrict__ er,
                                                    const int* __restrict__ ec, int E, int R,
                                                    int* __restrict__ bcur,
                                                    unsigned* __restrict__ packed) {
    __shared__ int h[NB];
    __shared__ int base[NB];
    for (int i = threadIdx.x; i < NB; i += 256) h[i] = 0;
    __syncthreads();
    int cb = blockIdx.x * 4096;
    int rows[16], cols[16], bks[16];
#pragma unroll
    for (int j = 0; j < 16; ++j) {
        int i = cb + j * 256 + threadIdx.x;
        if (i < E) {
            int r = er[i];
            rows[j] = r;
            cols[j] = ec[i];
            int b = r / R;
            bks[j] = b;
            atomicAdd(&h[b], 1);
        } else {
            bks[j] = -1;
        }
    }
    __syncthreads();
    for (int i = threadIdx.x; i < NB; i += 256)
        base[i] = h[i] ? atomicAdd(&bcur[i], h[i]) : 0;
    __syncthreads();
    for (int i = threadIdx.x; i < NB; i += 256) h[i] = 0;
    __syncthreads();
#pragma unroll
    for (int j = 0; j < 16; ++j) {
        int b = bks[j];
        if (b >= 0) {
            int off = atomicAdd(&h[b], 1);
            packed[base[b] + off] = ((unsigned)(rows[j] - b * R) << 16) | (unsigned)cols[j];
        }
    }
}

// ================= P2: per-bucket row_ptr/deg_inv + contiguous csr_col =================

__global__ __launch_bounds__(256) void p2_build_k(const unsigned* __restrict__ packed,
                                                  const int* __restrict__ bptr, int R, int N, int E,
                                                  int* __restrict__ row_ptr,
                                                  float* __restrict__ deginv,
                                                  int* __restrict__ csr_col) {
    __shared__ int hist[128];
    __shared__ int excl[129];
    __shared__ int cur[128];
    __shared__ int lcsr[2048];
    int b = blockIdx.x;
    int s = bptr[b], e = bptr[b + 1];
    int m = e - s;
    for (int i = threadIdx.x; i < 128; i += 256) hist[i] = 0;
    __syncthreads();
    for (int i = threadIdx.x; i < m; i += 256) atomicAdd(&hist[packed[s + i] >> 16], 1);
    __syncthreads();
    if (threadIdx.x == 0) {
        int acc = 0;
        for (int r = 0; r < R; ++r) { excl[r] = acc; acc += hist[r]; }
        excl[R] = acc;
    }
    __syncthreads();
    for (int r = threadIdx.x; r < R; r += 256) {
        int gr = b * R + r;
        if (gr < N) {
            row_ptr[gr] = s + excl[r];
            deginv[gr] = 1.0f / (float)(hist[r] + 1);  // +1 self loop
        }
        cur[r] = excl[r];
    }
    if (b == (int)gridDim.x - 1 && threadIdx.x == 0) row_ptr[N] = E;
    __syncthreads();
    if (m <= 2048) {
        for (int i = threadIdx.x; i < m; i += 256) {
            unsigned pk = packed[s + i];
            int pos = atomicAdd(&cur[pk >> 16], 1);
            lcsr[pos] = (int)(pk & 0xffffu);
        }
        __syncthreads();
        for (int i = threadIdx.x; i < m; i += 256) csr_col[s + i] = lcsr[i];
    } else {
        for (int i = threadIdx.x; i < m; i += 256) {
            unsigned pk = packed[s + i];
            int pos = atomicAdd(&cur[pk >> 16], 1);
            csr_col[s + pos] = (int)(pk & 0xffffu);
        }
    }
}

// ================= fused aggregate(+bias+relu) -> LDS -> GEMM =================
// Phase A: stage csr_col segment + row_ptr + deginv to LDS; 8 waves x 2 rows x 4 iters
// gather with 8 loads in flight (index chain reads LDS, not global).
// Phase B: 8-wave MFMA core: Cout = h @ Wt (+gemm_bias).

template <int NC, bool OUT_BF16>
__global__ __launch_bounds__(512) void fused_agg_gemm_k(const unsigned short* __restrict__ tin,
                                                        const int* __restrict__ row_ptr,
                                                        const int* __restrict__ csr_col,
                                                        const float* __restrict__ deginv,
                                                        const float* __restrict__ agg_bias,
                                                        const unsigned short* __restrict__ Wt,
                                                        const float* __restrict__ gemm_bias,
                                                        void* __restrict__ Cout, int n) {
    __shared__ unsigned short As[64 * 128];  // 16 KiB swizzled h-tile
    __shared__ int cols_s[2048];             // 8 KiB csr segment cache
    __shared__ int rp_s[65];
    __shared__ float di_s[64];
    const int t = threadIdx.x;
    const int row0 = blockIdx.x * 64;
    const int w = t >> 6;
    const int l = t & 63;
    const int half = l >> 5;
    const int sl = l & 31;
    const uint2* tw = (const uint2*)tin;
    const float4 bb = ((const float4*)agg_bias)[sl];

    // stage row_ptr (clamped), deginv (clamped) for this block's 64 rows
    if (t < 65) {
        int gr = row0 + t; if (gr > n) gr = n;
        rp_s[t] = row_ptr[gr];
    } else if (t < 129) {
        int gr = row0 + (t - 65); if (gr > n - 1) gr = n - 1;
        di_s[t - 65] = deginv[gr];
    }
    __syncthreads();
    const int seg0 = rp_s[0];
    {
        int seg_len = rp_s[64] - seg0;
        if (seg_len > 2048) seg_len = 2048;
        for (int i = t; i < seg_len; i += 512) cols_s[i] = csr_col[seg0 + i];
    }
    __syncthreads();

#pragma unroll
    for (int it = 0; it < 4; ++it) {
        int rl = it * 16 + w * 2 + half;
        int grow = row0 + rl; if (grow > n - 1) grow = n - 1;
        uint2 sv = tw[(size_t)grow * 32 + sl];  // self loop
        float a0 = bf16_to_f32((unsigned short)(sv.x & 0xffff));
        float a1 = bf16_to_f32((unsigned short)(sv.x >> 16));
        float a2 = bf16_to_f32((unsigned short)(sv.y & 0xffff));
        float a3 = bf16_to_f32((unsigned short)(sv.y >> 16));
        const int s = rp_s[rl], e = rp_s[rl + 1];
        const int d = e - s;
        if (e - seg0 <= 2048) {  // whole row's cols staged in LDS (hot path)
            const int loc = s - seg0;
            int p = 0;
            for (; p + 8 <= d; p += 8) {
                int c0 = cols_s[loc + p + 0];
                int c1 = cols_s[loc + p + 1];
                int c2 = cols_s[loc + p + 2];
                int c3 = cols_s[loc + p + 3];
                int c4 = cols_s[loc + p + 4];
                int c5 = cols_s[loc + p + 5];
                int c6 = cols_s[loc + p + 6];
                int c7 = cols_s[loc + p + 7];
                uint2 v0 = tw[(size_t)c0 * 32 + sl];
                uint2 v1 = tw[(size_t)c1 * 32 + sl];
                uint2 v2 = tw[(size_t)c2 * 32 + sl];
                uint2 v3 = tw[(size_t)c3 * 32 + sl];
                uint2 v4 = tw[(size_t)c4 * 32 + sl];
                uint2 v5 = tw[(size_t)c5 * 32 + sl];
                uint2 v6 = tw[(size_t)c6 * 32 + sl];
                uint2 v7 = tw[(size_t)c7 * 32 + sl];
                acc_uint2(a0, a1, a2, a3, v0);
                acc_uint2(a0, a1, a2, a3, v1);
                acc_uint2(a0, a1, a2, a3, v2);
                acc_uint2(a0, a1, a2, a3, v3);
                acc_uint2(a0, a1, a2, a3, v4);
                acc_uint2(a0, a1, a2, a3, v5);
                acc_uint2(a0, a1, a2, a3, v6);
                acc_uint2(a0, a1, a2, a3, v7);
            }
            for (; p < d; ++p) {
                int c = cols_s[loc + p];
                uint2 v = tw[(size_t)c * 32 + sl];
                acc_uint2(a0, a1, a2, a3, v);
            }
        } else {  // rare fallback: read cols from global
            for (int p = s; p < e; ++p) {
                int c = csr_col[p];
                uint2 v = tw[(size_t)c * 32 + sl];
                acc_uint2(a0, a1, a2, a3, v);
            }
        }
        float di = di_s[rl];
        float r0 = fmaxf(fmaf(a0, di, bb.x), 0.f);
        float r1 = fmaxf(fmaf(a1, di, bb.y), 0.f);
        float r2 = fmaxf(fmaf(a2, di, bb.z), 0.f);
        float r3 = fmaxf(fmaf(a3, di, bb.w), 0.f);
        uint2 pk;
        pk.x = (unsigned)bf16_rne(r0) | ((unsigned)bf16_rne(r1) << 16);
        pk.y = (unsigned)bf16_rne(r2) | ((unsigned)bf16_rne(r3) << 16);
        int byte = rl * 256 + ((sl * 8) ^ ((rl & 7) << 4));
        *(uint2*)((char*)As + byte) = pk;
    }
    __syncthreads();

    gemm_core<NC, OUT_BF16>(As, Wt, gemm_bias, Cout, row0, n);
}

// ================= launch =================

extern "C" void kernel_launch(void* const* d_in, const int* in_sizes, int n_in,
                              void* d_out, int out_size, void* d_ws, size_t ws_size,
                              hipStream_t stream) {
    const float* x  = (const float*)d_in[0];
    const int* edges = (const int*)d_in[1];
    const float* W1 = (const float*)d_in[2];
    const float* b1 = (const float*)d_in[3];
    const float* W2 = (const float*)d_in[4];
    const float* b2 = (const float*)d_in[5];
    const float* W3 = (const float*)d_in[6];
    const float* b3 = (const float*)d_in[7];
    const float* W4 = (const float*)d_in[8];
    const float* b4 = (const float*)d_in[9];

    const int N = in_sizes[0] / 128;
    const int E = in_sizes[1] / 2;
    const int NPAD = (N + 63) & ~63;
    const int R = (N + NB - 1) / NB;  // rows per bucket (98 for N=50000; kernels assume <=128)
    const int* e_row = edges;
    const int* e_col = edges + E;

    char* p = (char*)d_ws;
    auto alloc = [&](size_t bytes) {
        void* r = (void*)p;
        p += (bytes + 255) & ~(size_t)255;
        return r;
    };
    unsigned short* t_bf = (unsigned short*)alloc((size_t)NPAD * 128 * 2);
    unsigned short* t2_bf = (unsigned short*)alloc((size_t)NPAD * 128 * 2);
    float* deginv  = (float*)alloc((size_t)N * 4);
    int*   row_ptr = (int*)alloc((size_t)(N + 1) * 4);
    int*   csr_col = (int*)alloc((size_t)E * 4);
    unsigned* packed = (unsigned*)alloc((size_t)E * 4);
    int*   bucket_cnt = (int*)alloc(NB * 4);
    int*   bucket_ptr = (int*)alloc((NB + 1) * 4);
    int*   bucket_cur = (int*)alloc(NB * 4);
    unsigned short* w1t = (unsigned short*)alloc(128 * 128 * 2);
    unsigned short* w2t = (unsigned short*)alloc(128 * 128 * 2);
    unsigned short* wft = (unsigned short*)alloc(64 * 128 * 2);
    float* bfv     = (float*)alloc(64 * 4);

    float* out = (float*)d_out;

    hipMemsetAsync(bucket_cnt, 0, NB * 4, stream);

    const int PB = (E + 8191) / 8192;       // p0 blocks (512 thr x 16)
    const int WB = (41024 + 511) / 512;     // weight-prep blocks
    const int gblocks = NPAD / 64;

    // d1: edge bucket histogram + weight prep (independent)
    prep_p0_k<<<PB + WB, 512, 0, stream>>>(e_row, E, R, bucket_cnt, PB,
                                           W1, W2, W3, b3, W4, b4, w1t, w2t, wft, bfv);
    // d2: GEMM1 (t1 = x @ W1) + bucket scan
    gemm1_p0b_k<<<gblocks + 1, 512, 0, stream>>>(x, w1t, t_bf, N, gblocks,
                                                 bucket_cnt, bucket_ptr, bucket_cur, E);
    // d3, d4: CSR build
    p1_scatter_k<<<(E + 4095) / 4096, 256, 0, stream>>>(e_row, e_col, E, R, bucket_cur, packed);
    p2_build_k<<<NB, 256, 0, stream>>>(packed, bucket_ptr, R, N, E, row_ptr, deginv, csr_col);

    // d5: h1 = relu(D^-1 A t1 + b1) -> LDS ; t2 = h1 @ W2 (bf16, padded)
    fused_agg_gemm_k<128, true><<<gblocks, 512, 0, stream>>>(
        t_bf, row_ptr, csr_col, deginv, b1, w2t, nullptr, t2_bf, N);
    // d6: h2 = relu(D^-1 A t2 + b2) -> LDS ; out = h2 @ (W3@W4) + (b3@W4+b4) (f32, masked)
    fused_agg_gemm_k<64, false><<<gblocks, 512, 0, stream>>>(
        t2_bf, row_ptr, csr_col, deginv, b2, wft, bfv, out, N);
}